// Round 1
// baseline (423.539 us; speedup 1.0000x reference)
//
#include <hip/hip_runtime.h>
#include <math.h>

// Problem constants (match reference)
//   N=50000 nodes, E=800000 edges, IN=128, HID=64, HEADS=2 -> HEADS*HID=128, OUT=64

__device__ __forceinline__ float lrelu02(float x){ return x > 0.f ? x : 0.2f * x; }

__device__ __forceinline__ float wave_max(float v){
#pragma unroll
  for (int o = 32; o > 0; o >>= 1) v = fmaxf(v, __shfl_xor(v, o));
  return v;
}
__device__ __forceinline__ float wave_sum(float v){
#pragma unroll
  for (int o = 32; o > 0; o >>= 1) v += __shfl_xor(v, o);
  return v;
}

// ---------------- GEMM1: h[n][128] = x[n][128] @ W1[128][128] ----------------
__global__ __launch_bounds__(256) void gemm1_kernel(const float* __restrict__ x,
                                                    const float* __restrict__ W1,
                                                    float* __restrict__ h, int n){
  __shared__ float xs[16][128];
  int br = blockIdx.x * 16;
  for (int t = threadIdx.x; t < 16 * 128; t += 256){
    int r = t >> 7, c = t & 127;
    int row = br + r;
    xs[r][c] = (row < n) ? x[row * 128 + c] : 0.f;
  }
  __syncthreads();
  int col = threadIdx.x & 127;
  int rh  = threadIdx.x >> 7;  // 0 or 1 -> rows 0..7 / 8..15
  float acc[8];
#pragma unroll
  for (int r = 0; r < 8; r++) acc[r] = 0.f;
  for (int k2 = 0; k2 < 128; k2++){
    float w = W1[k2 * 128 + col];
#pragma unroll
    for (int r = 0; r < 8; r++) acc[r] = fmaf(xs[rh * 8 + r][k2], w, acc[r]);
  }
#pragma unroll
  for (int r = 0; r < 8; r++){
    int row = br + rh * 8 + r;
    if (row < n) h[row * 128 + col] = acc[r];
  }
}

// -------- per-node attention coefficients: a_src/a_dst [n][2] --------
__global__ __launch_bounds__(256) void attn_coef_kernel(const float* __restrict__ h,
                                                        const float* __restrict__ att_src,
                                                        const float* __restrict__ att_dst,
                                                        float* __restrict__ asrc,
                                                        float* __restrict__ adst, int n){
  int node = blockIdx.x * 4 + (threadIdx.x >> 6);
  int lane = threadIdx.x & 63;
  if (node >= n) return;
  float h0 = h[node * 128 + lane];
  float h1 = h[node * 128 + 64 + lane];
  float as0 = wave_sum(h0 * att_src[lane]);
  float as1 = wave_sum(h1 * att_src[64 + lane]);
  float ad0 = wave_sum(h0 * att_dst[lane]);
  float ad1 = wave_sum(h1 * att_dst[64 + lane]);
  if (lane == 0){
    asrc[node * 2 + 0] = as0; asrc[node * 2 + 1] = as1;
    adst[node * 2 + 0] = ad0; adst[node * 2 + 1] = ad1;
  }
}

// ---------------- CSR build ----------------
__global__ __launch_bounds__(256) void count_deg_kernel(const int* __restrict__ dst,
                                                        int* __restrict__ counts, int E){
  int e = blockIdx.x * 256 + threadIdx.x;
  if (e < E) atomicAdd(&counts[dst[e]], 1);
}

__global__ __launch_bounds__(1024) void scan_kernel(const int* __restrict__ counts,
                                                    int* __restrict__ offsets, int n){
  __shared__ int buf[2][1024];
  int carry = 0;
  const int CH = 8192;
  for (int base = 0; base < n; base += CH){
    int local[8]; int lsum = 0;
#pragma unroll
    for (int j = 0; j < 8; j++){
      int i = base + threadIdx.x * 8 + j;
      int v = (i < n) ? counts[i] : 0;
      local[j] = lsum;   // exclusive within thread
      lsum += v;
    }
    buf[0][threadIdx.x] = lsum;
    __syncthreads();
    int cur = 0;
    for (int off = 1; off < 1024; off <<= 1){
      int t = buf[cur][threadIdx.x];
      if ((int)threadIdx.x >= off) t += buf[cur][threadIdx.x - off];
      buf[cur ^ 1][threadIdx.x] = t;
      __syncthreads();
      cur ^= 1;
    }
    int excl = carry + (threadIdx.x > 0 ? buf[cur][threadIdx.x - 1] : 0);
#pragma unroll
    for (int j = 0; j < 8; j++){
      int i = base + threadIdx.x * 8 + j;
      if (i < n) offsets[i] = excl + local[j];
    }
    carry += buf[cur][1023];
    __syncthreads();
  }
  if (threadIdx.x == 0) offsets[n] = carry;
}

__global__ __launch_bounds__(256) void fill_csr_kernel(const int* __restrict__ src,
                                                       const int* __restrict__ dst,
                                                       int* __restrict__ cursor,
                                                       int* __restrict__ csr_src, int E){
  int e = blockIdx.x * 256 + threadIdx.x;
  if (e < E){
    int pos = atomicAdd(&cursor[dst[e]], 1);
    csr_src[pos] = src[e];
  }
}

// ---------------- GAT aggregation: one wave per node ----------------
__global__ __launch_bounds__(256) void gat_agg_kernel(const float* __restrict__ h,
                                                      const float* __restrict__ asrc,
                                                      const float* __restrict__ adst,
                                                      const int* __restrict__ off,
                                                      const int* __restrict__ csr_src,
                                                      const float* __restrict__ b1,
                                                      float* __restrict__ x1, int n){
  int node = blockIdx.x * 4 + (threadIdx.x >> 6);
  int lane = threadIdx.x & 63;
  if (node >= n) return;
  int s0 = off[node];
  int d  = off[node + 1] - s0;
  float2 ad = ((const float2*)adst)[node];
  float2 as_self = ((const float2*)asrc)[node];
  float e_self0 = lrelu02(as_self.x + ad.x);
  float e_self1 = lrelu02(as_self.y + ad.y);
  // pass 1: segment max (self-loop included)
  float m0 = e_self0, m1 = e_self1;
  for (int base = 0; base < d; base += 64){
    int idx = base + lane;
    bool valid = idx < d;
    int sj = valid ? csr_src[s0 + idx] : 0;
    float2 as = ((const float2*)asrc)[sj];
    float e0 = valid ? lrelu02(as.x + ad.x) : -3.0e38f;
    float e1 = valid ? lrelu02(as.y + ad.y) : -3.0e38f;
    m0 = fmaxf(m0, e0); m1 = fmaxf(m1, e1);
  }
  m0 = wave_max(m0); m1 = wave_max(m1);
  // pass 2: accumulate p = exp(e-m), channels = lanes, normalize at end
  float pself0 = __expf(e_self0 - m0) /* exact enough */, pself1 = __expf(e_self1 - m1);
  pself0 = expf(e_self0 - m0); pself1 = expf(e_self1 - m1);
  float acc0 = pself0 * h[node * 128 + lane];
  float acc1 = pself1 * h[node * 128 + 64 + lane];
  float ps0 = 0.f, ps1 = 0.f;
  for (int base = 0; base < d; base += 64){
    int idx = base + lane;
    bool valid = idx < d;
    int sj = valid ? csr_src[s0 + idx] : 0;
    float2 as = ((const float2*)asrc)[sj];
    float p0 = valid ? expf(lrelu02(as.x + ad.x) - m0) : 0.f;
    float p1 = valid ? expf(lrelu02(as.y + ad.y) - m1) : 0.f;
    ps0 += p0; ps1 += p1;
    int cn = min(64, d - base);
    for (int j = 0; j < cn; j++){
      float a0 = __shfl(p0, j);
      float a1 = __shfl(p1, j);
      int sjj  = __shfl(sj, j);
      const float* hrow = h + (size_t)sjj * 128;
      acc0 = fmaf(a0, hrow[lane], acc0);
      acc1 = fmaf(a1, hrow[64 + lane], acc1);
    }
  }
  float s0t = pself0 + wave_sum(ps0);
  float s1t = pself1 + wave_sum(ps1);
  float v0 = acc0 / s0t + b1[lane];
  float v1 = acc1 / s1t + b1[64 + lane];
  x1[node * 128 + lane]      = fmaxf(v0, 0.f);
  x1[node * 128 + 64 + lane] = fmaxf(v1, 0.f);
}

// -------- GEMM2: q,k,v,skip = x1 @ {Wq,Wk,Wv,Wskip} + biases --------
__global__ __launch_bounds__(256) void gemm2_kernel(const float* __restrict__ x1,
                                                    const float* __restrict__ Wq,
                                                    const float* __restrict__ Wk,
                                                    const float* __restrict__ Wv,
                                                    const float* __restrict__ Ws,
                                                    const float* __restrict__ bq,
                                                    const float* __restrict__ bk,
                                                    const float* __restrict__ bv,
                                                    const float* __restrict__ bs,
                                                    float* __restrict__ q,
                                                    float* __restrict__ k,
                                                    float* __restrict__ v,
                                                    float* __restrict__ skip, int n){
  __shared__ float xs[16][128];
  int br = blockIdx.x * 16;
  for (int t = threadIdx.x; t < 16 * 128; t += 256){
    int r = t >> 7, c = t & 127;
    int row = br + r;
    xs[r][c] = (row < n) ? x1[row * 128 + c] : 0.f;
  }
  __syncthreads();
  int mat = threadIdx.x >> 6;   // wave-uniform
  int c   = threadIdx.x & 63;
  const float* W  = (mat == 0) ? Wq : (mat == 1) ? Wk : (mat == 2) ? Wv : Ws;
  const float* bb = (mat == 0) ? bq : (mat == 1) ? bk : (mat == 2) ? bv : bs;
  float* out      = (mat == 0) ? q  : (mat == 1) ? k  : (mat == 2) ? v  : skip;
  float acc[16];
#pragma unroll
  for (int r = 0; r < 16; r++) acc[r] = 0.f;
  for (int k2 = 0; k2 < 128; k2++){
    float w = W[k2 * 64 + c];
#pragma unroll
    for (int r = 0; r < 16; r++) acc[r] = fmaf(xs[r][k2], w, acc[r]);
  }
  float bias = bb[c];
#pragma unroll
  for (int r = 0; r < 16; r++){
    int row = br + r;
    if (row < n) out[row * 64 + c] = acc[r] + bias;
  }
}

// ---------- Transformer aggregation + log_softmax: one wave per node ----------
__global__ __launch_bounds__(256) void trans_agg_kernel(const float* __restrict__ q,
                                                        const float* __restrict__ k,
                                                        const float* __restrict__ v,
                                                        const float* __restrict__ skip,
                                                        const int* __restrict__ off,
                                                        const int* __restrict__ csr_src,
                                                        float* __restrict__ out,
                                                        float* __restrict__ score_ws, int n){
  int node = blockIdx.x * 4 + (threadIdx.x >> 6);
  int lane = threadIdx.x & 63;
  if (node >= n) return;
  int s0 = off[node];
  int d  = off[node + 1] - s0;
  float q_l = q[node * 64 + lane];
  // pass 1: scores (cached to scratch) + segment max
  float m = -3.0e38f;
  for (int base = 0; base < d; base += 64){
    int idx = base + lane;
    bool valid = idx < d;
    int sj = valid ? csr_src[s0 + idx] : 0;
    const float4* k4 = (const float4*)(k + (size_t)sj * 64);
    float dot = 0.f;
#pragma unroll 4
    for (int j4 = 0; j4 < 16; j4++){
      float4 kv = k4[j4];
      dot = fmaf(__shfl(q_l, 4 * j4 + 0), kv.x, dot);
      dot = fmaf(__shfl(q_l, 4 * j4 + 1), kv.y, dot);
      dot = fmaf(__shfl(q_l, 4 * j4 + 2), kv.z, dot);
      dot = fmaf(__shfl(q_l, 4 * j4 + 3), kv.w, dot);
    }
    float sc = dot * 0.125f;
    if (valid) score_ws[s0 + idx] = sc; else sc = -3.0e38f;
    m = fmaxf(m, sc);
  }
  m = wave_max(m);
  // pass 2: p = exp(sc-m); serial broadcast accumulate of v rows
  float ps = 0.f, acc = 0.f;
  for (int base = 0; base < d; base += 64){
    int idx = base + lane;
    bool valid = idx < d;
    int sj = valid ? csr_src[s0 + idx] : 0;
    float p = valid ? expf(score_ws[s0 + idx] - m) : 0.f;
    ps += p;
    int cn = min(64, d - base);
    for (int j = 0; j < cn; j++){
      float a  = __shfl(p, j);
      int sjj  = __shfl(sj, j);
      acc = fmaf(a, v[(size_t)sjj * 64 + lane], acc);
    }
  }
  ps = wave_sum(ps);
  float val = skip[node * 64 + lane];
  if (d > 0) val += acc / ps;
  // fused log_softmax over the 64 lanes
  float mx = wave_max(val);
  float t  = val - mx;
  float se = wave_sum(expf(t));
  out[node * 64 + lane] = t - logf(se);
}

extern "C" void kernel_launch(void* const* d_in, const int* in_sizes, int n_in,
                              void* d_out, int out_size, void* d_ws, size_t ws_size,
                              hipStream_t stream) {
  const float* x       = (const float*)d_in[0];
  const int*   ei      = (const int*)d_in[1];
  const float* W1      = (const float*)d_in[2];
  const float* att_src = (const float*)d_in[3];
  const float* att_dst = (const float*)d_in[4];
  const float* b1      = (const float*)d_in[5];
  const float* Wq = (const float*)d_in[6];  const float* bq = (const float*)d_in[7];
  const float* Wk = (const float*)d_in[8];  const float* bk = (const float*)d_in[9];
  const float* Wv = (const float*)d_in[10]; const float* bv = (const float*)d_in[11];
  const float* Ws = (const float*)d_in[12]; const float* bs = (const float*)d_in[13];
  float* out = (float*)d_out;

  int n = in_sizes[0] / 128;
  int E = in_sizes[1] / 2;
  const int* src = ei;
  const int* dst = ei + E;

  // workspace layout (~85 MB)
  char* w = (char*)d_ws;
  auto alloc = [&](size_t bytes) -> void* {
    void* p = (void*)w;
    w += (bytes + 255) & ~(size_t)255;
    return p;
  };
  float* h    = (float*)alloc((size_t)n * 128 * 4);   // later reused for q|k
  float* asrc = (float*)alloc((size_t)n * 2 * 4);
  float* adst = (float*)alloc((size_t)n * 2 * 4);
  float* x1   = (float*)alloc((size_t)n * 128 * 4);
  float* vv   = (float*)alloc((size_t)n * 64 * 4);
  float* skip = (float*)alloc((size_t)n * 64 * 4);
  int* counts  = (int*)alloc((size_t)n * 4);
  int* offsets = (int*)alloc((size_t)(n + 1) * 4);
  int* csr     = (int*)alloc((size_t)E * 4);
  float* scw   = (float*)alloc((size_t)E * 4);
  float* qq = h;                 // reuse h after gat_agg
  float* kk = h + (size_t)n * 64;

  // CSR build (dst-grouped)
  hipMemsetAsync(counts, 0, (size_t)n * 4, stream);
  count_deg_kernel<<<(E + 255) / 256, 256, 0, stream>>>(dst, counts, E);
  scan_kernel<<<1, 1024, 0, stream>>>(counts, offsets, n);
  hipMemcpyAsync(counts, offsets, (size_t)n * 4, hipMemcpyDeviceToDevice, stream); // counts -> cursor
  fill_csr_kernel<<<(E + 255) / 256, 256, 0, stream>>>(src, dst, counts, csr, E);

  // GAT layer
  gemm1_kernel<<<(n + 15) / 16, 256, 0, stream>>>(x, W1, h, n);
  attn_coef_kernel<<<(n + 3) / 4, 256, 0, stream>>>(h, att_src, att_dst, asrc, adst, n);
  gat_agg_kernel<<<(n + 3) / 4, 256, 0, stream>>>(h, asrc, adst, offsets, csr, b1, x1, n);

  // Transformer layer
  gemm2_kernel<<<(n + 15) / 16, 256, 0, stream>>>(x1, Wq, Wk, Wv, Ws, bq, bk, bv, bs,
                                                  qq, kk, vv, skip, n);
  trans_agg_kernel<<<(n + 3) / 4, 256, 0, stream>>>(qq, kk, vv, skip, offsets, csr,
                                                    out, scw, n);
}

// Round 2
// 409.261 us; speedup vs baseline: 1.0349x; 1.0349x over previous
//
#include <hip/hip_runtime.h>
#include <math.h>

typedef unsigned short u16;
typedef unsigned int u32;

__device__ __forceinline__ float lrelu02(float x){ return x > 0.f ? x : 0.2f * x; }

__device__ __forceinline__ float bf2f(u16 u){
  union { u32 i; float f; } v; v.i = ((u32)u) << 16; return v.f;
}
__device__ __forceinline__ u16 f2bf(float f){
  union { float ff; u32 i; } v; v.ff = f;
  u32 x = v.i;
  return (u16)((x + 0x7fffu + ((x >> 16) & 1u)) >> 16);  // RNE, no NaN inputs here
}

__device__ __forceinline__ float wave_max(float v){
#pragma unroll
  for (int o = 32; o > 0; o >>= 1) v = fmaxf(v, __shfl_xor(v, o));
  return v;
}
__device__ __forceinline__ float wave_sum(float v){
#pragma unroll
  for (int o = 32; o > 0; o >>= 1) v += __shfl_xor(v, o);
  return v;
}

// ---------------- GEMM1: h2[n][128](bf16) = x[n][128] @ W1[128][128] ----------------
__global__ __launch_bounds__(256) void gemm1_kernel(const float* __restrict__ x,
                                                    const float* __restrict__ W1,
                                                    u16* __restrict__ h2, int n){
  __shared__ float xs[16][128];
  int br = blockIdx.x * 16;
  const float4* x4 = (const float4*)x;
  for (int t = threadIdx.x; t < 512; t += 256){
    int r = t >> 5, c4 = t & 31;
    int row = br + r;
    float4 v = {0.f, 0.f, 0.f, 0.f};
    if (row < n) v = x4[(size_t)row * 32 + c4];
    *(float4*)&xs[r][c4 * 4] = v;
  }
  __syncthreads();
  int col = threadIdx.x & 127;
  int rh  = threadIdx.x >> 7;
  float acc[8];
#pragma unroll
  for (int r = 0; r < 8; r++) acc[r] = 0.f;
  for (int k4 = 0; k4 < 128; k4 += 4){
    float w0 = W1[(k4 + 0) * 128 + col];
    float w1 = W1[(k4 + 1) * 128 + col];
    float w2 = W1[(k4 + 2) * 128 + col];
    float w3 = W1[(k4 + 3) * 128 + col];
#pragma unroll
    for (int r = 0; r < 8; r++){
      float4 xv = *(const float4*)&xs[rh * 8 + r][k4];
      acc[r] = fmaf(xv.x, w0, acc[r]);
      acc[r] = fmaf(xv.y, w1, acc[r]);
      acc[r] = fmaf(xv.z, w2, acc[r]);
      acc[r] = fmaf(xv.w, w3, acc[r]);
    }
  }
#pragma unroll
  for (int r = 0; r < 8; r++){
    int row = br + rh * 8 + r;
    if (row < n) h2[(size_t)row * 128 + col] = f2bf(acc[r]);
  }
}

// -------- per-node attention coefficients: a_src/a_dst [n][2] --------
__global__ __launch_bounds__(256) void attn_coef_kernel(const u16* __restrict__ h2,
                                                        const float* __restrict__ att_src,
                                                        const float* __restrict__ att_dst,
                                                        float* __restrict__ asrc,
                                                        float* __restrict__ adst, int n){
  int node = blockIdx.x * 4 + (threadIdx.x >> 6);
  int lane = threadIdx.x & 63;
  if (node >= n) return;
  float h0 = bf2f(h2[(size_t)node * 128 + lane]);
  float h1 = bf2f(h2[(size_t)node * 128 + 64 + lane]);
  float as0 = wave_sum(h0 * att_src[lane]);
  float as1 = wave_sum(h1 * att_src[64 + lane]);
  float ad0 = wave_sum(h0 * att_dst[lane]);
  float ad1 = wave_sum(h1 * att_dst[64 + lane]);
  if (lane == 0){
    asrc[node * 2 + 0] = as0; asrc[node * 2 + 1] = as1;
    adst[node * 2 + 0] = ad0; adst[node * 2 + 1] = ad1;
  }
}

// ---------------- CSR build ----------------
__global__ __launch_bounds__(256) void count_deg_kernel(const int* __restrict__ dst,
                                                        int* __restrict__ counts, int E){
  int e = blockIdx.x * 256 + threadIdx.x;
  if (e < E) atomicAdd(&counts[dst[e]], 1);
}

__global__ __launch_bounds__(1024) void scan_kernel(const int* __restrict__ counts,
                                                    int* __restrict__ offsets, int n){
  __shared__ int buf[2][1024];
  int carry = 0;
  const int CH = 8192;
  for (int base = 0; base < n; base += CH){
    int local[8]; int lsum = 0;
#pragma unroll
    for (int j = 0; j < 8; j++){
      int i = base + threadIdx.x * 8 + j;
      int v = (i < n) ? counts[i] : 0;
      local[j] = lsum;
      lsum += v;
    }
    buf[0][threadIdx.x] = lsum;
    __syncthreads();
    int cur = 0;
    for (int off = 1; off < 1024; off <<= 1){
      int t = buf[cur][threadIdx.x];
      if ((int)threadIdx.x >= off) t += buf[cur][threadIdx.x - off];
      buf[cur ^ 1][threadIdx.x] = t;
      __syncthreads();
      cur ^= 1;
    }
    int excl = carry + (threadIdx.x > 0 ? buf[cur][threadIdx.x - 1] : 0);
#pragma unroll
    for (int j = 0; j < 8; j++){
      int i = base + threadIdx.x * 8 + j;
      if (i < n) offsets[i] = excl + local[j];
    }
    carry += buf[cur][1023];
    __syncthreads();
  }
  if (threadIdx.x == 0) offsets[n] = carry;
}

__global__ __launch_bounds__(256) void fill_csr_kernel(const int* __restrict__ src,
                                                       const int* __restrict__ dst,
                                                       int* __restrict__ cursor,
                                                       int* __restrict__ csr_src, int E){
  int e = blockIdx.x * 256 + threadIdx.x;
  if (e < E){
    int pos = atomicAdd(&cursor[dst[e]], 1);
    csr_src[pos] = src[e];
  }
}

// ---------------- GAT aggregation: one wave per node ----------------
__global__ __launch_bounds__(256) void gat_agg_kernel(const u16* __restrict__ h2,
                                                      const float* __restrict__ asrc,
                                                      const float* __restrict__ adst,
                                                      const int* __restrict__ off,
                                                      const int* __restrict__ csr_src,
                                                      const float* __restrict__ b1,
                                                      u16* __restrict__ x1bf, int n){
  int node = blockIdx.x * 4 + (threadIdx.x >> 6);
  int lane = threadIdx.x & 63;
  if (node >= n) return;
  int s0 = off[node];
  int d  = off[node + 1] - s0;
  float2 ad = ((const float2*)adst)[node];
  float2 asl = ((const float2*)asrc)[node];
  float e_self0 = lrelu02(asl.x + ad.x);
  float e_self1 = lrelu02(asl.y + ad.y);
  float m0 = e_self0, m1 = e_self1;
  for (int base = 0; base < d; base += 64){
    int idx = base + lane;
    bool valid = idx < d;
    int sj = valid ? csr_src[s0 + idx] : 0;
    float2 as = ((const float2*)asrc)[sj];
    float e0 = valid ? lrelu02(as.x + ad.x) : -3.0e38f;
    float e1 = valid ? lrelu02(as.y + ad.y) : -3.0e38f;
    m0 = fmaxf(m0, e0); m1 = fmaxf(m1, e1);
  }
  m0 = wave_max(m0); m1 = wave_max(m1);
  float pself0 = __expf(e_self0 - m0), pself1 = __expf(e_self1 - m1);
  float acc0 = pself0 * bf2f(h2[(size_t)node * 128 + lane]);
  float acc1 = pself1 * bf2f(h2[(size_t)node * 128 + 64 + lane]);
  float ps0 = 0.f, ps1 = 0.f;
  for (int base = 0; base < d; base += 64){
    int idx = base + lane;
    bool valid = idx < d;
    int sj = valid ? csr_src[s0 + idx] : 0;
    float2 as = ((const float2*)asrc)[sj];
    float p0 = valid ? __expf(lrelu02(as.x + ad.x) - m0) : 0.f;
    float p1 = valid ? __expf(lrelu02(as.y + ad.y) - m1) : 0.f;
    ps0 += p0; ps1 += p1;
    int cn = min(64, d - base);
#pragma unroll 4
    for (int j = 0; j < cn; j++){
      float a0 = __shfl(p0, j);
      float a1 = __shfl(p1, j);
      int sjj  = __shfl(sj, j);
      const u16* hr = h2 + (size_t)sjj * 128;
      acc0 = fmaf(a0, bf2f(hr[lane]), acc0);
      acc1 = fmaf(a1, bf2f(hr[64 + lane]), acc1);
    }
  }
  float s0t = pself0 + wave_sum(ps0);
  float s1t = pself1 + wave_sum(ps1);
  float v0 = acc0 / s0t + b1[lane];
  float v1 = acc1 / s1t + b1[64 + lane];
  x1bf[(size_t)node * 128 + lane]      = f2bf(fmaxf(v0, 0.f));
  x1bf[(size_t)node * 128 + 64 + lane] = f2bf(fmaxf(v1, 0.f));
}

// -------- GEMM2: q,k,v,skip = x1 @ {Wq,Wk,Wv,Wskip} + biases --------
__global__ __launch_bounds__(256) void gemm2_kernel(const u16* __restrict__ x1bf,
                                                    const float* __restrict__ Wq,
                                                    const float* __restrict__ Wk,
                                                    const float* __restrict__ Wv,
                                                    const float* __restrict__ Ws,
                                                    const float* __restrict__ bq,
                                                    const float* __restrict__ bk,
                                                    const float* __restrict__ bv,
                                                    const float* __restrict__ bs,
                                                    float* __restrict__ q,
                                                    u16* __restrict__ k2,
                                                    u16* __restrict__ v2,
                                                    float* __restrict__ skip, int n){
  __shared__ float xs[16][128];
  int br = blockIdx.x * 16;
  const u32* xu = (const u32*)x1bf;   // 2 bf16 per u32
  for (int t = threadIdx.x; t < 1024; t += 256){
    int r = t >> 6, cu = t & 63;
    int row = br + r;
    u32 u = (row < n) ? xu[(size_t)row * 64 + cu] : 0u;
    xs[r][cu * 2]     = bf2f((u16)(u & 0xffffu));
    xs[r][cu * 2 + 1] = bf2f((u16)(u >> 16));
  }
  __syncthreads();
  int mat = threadIdx.x >> 6;   // wave-uniform
  int c   = threadIdx.x & 63;
  const float* W  = (mat == 0) ? Wq : (mat == 1) ? Wk : (mat == 2) ? Wv : Ws;
  const float* bb = (mat == 0) ? bq : (mat == 1) ? bk : (mat == 2) ? bv : bs;
  float acc[16];
#pragma unroll
  for (int r = 0; r < 16; r++) acc[r] = 0.f;
  for (int k4 = 0; k4 < 128; k4 += 4){
    float w0 = W[(k4 + 0) * 64 + c];
    float w1 = W[(k4 + 1) * 64 + c];
    float w2 = W[(k4 + 2) * 64 + c];
    float w3 = W[(k4 + 3) * 64 + c];
#pragma unroll
    for (int r = 0; r < 16; r++){
      float4 xv = *(const float4*)&xs[r][k4];
      acc[r] = fmaf(xv.x, w0, acc[r]);
      acc[r] = fmaf(xv.y, w1, acc[r]);
      acc[r] = fmaf(xv.z, w2, acc[r]);
      acc[r] = fmaf(xv.w, w3, acc[r]);
    }
  }
  float bias = bb[c];
#pragma unroll
  for (int r = 0; r < 16; r++){
    int row = br + r;
    if (row >= n) continue;
    float val = acc[r] + bias;
    if (mat == 0)      q[(size_t)row * 64 + c]    = val;
    else if (mat == 1) k2[(size_t)row * 64 + c]   = f2bf(val);
    else if (mat == 2) v2[(size_t)row * 64 + c]   = f2bf(val);
    else               skip[(size_t)row * 64 + c] = val;
  }
}

// ---------- Transformer aggregation + log_softmax: one wave per node ----------
__global__ __launch_bounds__(256) void trans_agg_kernel(const float* __restrict__ q,
                                                        const u16* __restrict__ k2,
                                                        const u16* __restrict__ v2,
                                                        const float* __restrict__ skip,
                                                        const int* __restrict__ off,
                                                        const int* __restrict__ csr_src,
                                                        float* __restrict__ out,
                                                        float* __restrict__ score_ws, int n){
  int node = blockIdx.x * 4 + (threadIdx.x >> 6);
  int lane = threadIdx.x & 63;
  if (node >= n) return;
  int s0 = off[node];
  int d  = off[node + 1] - s0;
  int sub = lane & 3;
  // this lane's 16-channel slice of q for 4-lane-group dot products
  const float* qp = q + (size_t)node * 64 + sub * 16;
  float4 qa = *(const float4*)(qp + 0);
  float4 qb = *(const float4*)(qp + 4);
  float4 qc = *(const float4*)(qp + 8);
  float4 qd = *(const float4*)(qp + 12);
  // pass 1: scores (cached to scratch) + segment max; 16 edges per iter, 4 lanes/edge
  float m = -3.0e38f;
  for (int base = 0; base < d; base += 16){
    int eidx = base + (lane >> 2);
    bool valid = eidx < d;
    int sj = valid ? csr_src[s0 + eidx] : 0;
    const uint4* kp = (const uint4*)(k2 + (size_t)sj * 64 + sub * 16);
    uint4 ka = kp[0], kb = kp[1];
    float dot = 0.f;
    dot = fmaf(qa.x, bf2f((u16)(ka.x & 0xffffu)), dot);
    dot = fmaf(qa.y, bf2f((u16)(ka.x >> 16)), dot);
    dot = fmaf(qa.z, bf2f((u16)(ka.y & 0xffffu)), dot);
    dot = fmaf(qa.w, bf2f((u16)(ka.y >> 16)), dot);
    dot = fmaf(qb.x, bf2f((u16)(ka.z & 0xffffu)), dot);
    dot = fmaf(qb.y, bf2f((u16)(ka.z >> 16)), dot);
    dot = fmaf(qb.z, bf2f((u16)(ka.w & 0xffffu)), dot);
    dot = fmaf(qb.w, bf2f((u16)(ka.w >> 16)), dot);
    dot = fmaf(qc.x, bf2f((u16)(kb.x & 0xffffu)), dot);
    dot = fmaf(qc.y, bf2f((u16)(kb.x >> 16)), dot);
    dot = fmaf(qc.z, bf2f((u16)(kb.y & 0xffffu)), dot);
    dot = fmaf(qc.w, bf2f((u16)(kb.y >> 16)), dot);
    dot = fmaf(qd.x, bf2f((u16)(kb.z & 0xffffu)), dot);
    dot = fmaf(qd.y, bf2f((u16)(kb.z >> 16)), dot);
    dot = fmaf(qd.z, bf2f((u16)(kb.w & 0xffffu)), dot);
    dot = fmaf(qd.w, bf2f((u16)(kb.w >> 16)), dot);
    dot += __shfl_xor(dot, 1);
    dot += __shfl_xor(dot, 2);
    float sc = dot * 0.125f;
    if (valid && sub == 0) score_ws[s0 + eidx] = sc;
    m = fmaxf(m, valid ? sc : -3.0e38f);
  }
  m = wave_max(m);
  // pass 2: p = exp(sc-m); serial broadcast accumulate of v rows (bf16)
  float ps = 0.f, acc = 0.f;
  for (int base = 0; base < d; base += 64){
    int idx = base + lane;
    bool valid = idx < d;
    int sj = valid ? csr_src[s0 + idx] : 0;
    float p = valid ? __expf(score_ws[s0 + idx] - m) : 0.f;
    ps += p;
    int cn = min(64, d - base);
#pragma unroll 4
    for (int j = 0; j < cn; j++){
      float a  = __shfl(p, j);
      int sjj  = __shfl(sj, j);
      acc = fmaf(a, bf2f(v2[(size_t)sjj * 64 + lane]), acc);
    }
  }
  ps = wave_sum(ps);
  float val = skip[(size_t)node * 64 + lane];
  if (d > 0) val += acc / ps;
  float mx = wave_max(val);
  float t  = val - mx;
  float se = wave_sum(__expf(t));
  out[(size_t)node * 64 + lane] = t - __logf(se);
}

extern "C" void kernel_launch(void* const* d_in, const int* in_sizes, int n_in,
                              void* d_out, int out_size, void* d_ws, size_t ws_size,
                              hipStream_t stream) {
  const float* x       = (const float*)d_in[0];
  const int*   ei      = (const int*)d_in[1];
  const float* W1      = (const float*)d_in[2];
  const float* att_src = (const float*)d_in[3];
  const float* att_dst = (const float*)d_in[4];
  const float* b1      = (const float*)d_in[5];
  const float* Wq = (const float*)d_in[6];  const float* bq = (const float*)d_in[7];
  const float* Wk = (const float*)d_in[8];  const float* bk = (const float*)d_in[9];
  const float* Wv = (const float*)d_in[10]; const float* bv = (const float*)d_in[11];
  const float* Ws = (const float*)d_in[12]; const float* bs = (const float*)d_in[13];
  float* out = (float*)d_out;

  int n = in_sizes[0] / 128;
  int E = in_sizes[1] / 2;
  const int* src = ei;
  const int* dst = ei + E;

  char* w = (char*)d_ws;
  auto alloc = [&](size_t bytes) -> void* {
    void* p = (void*)w;
    w += (bytes + 255) & ~(size_t)255;
    return p;
  };
  u16*  h2   = (u16*)alloc((size_t)n * 128 * 2);      // bf16 h
  float* asrc = (float*)alloc((size_t)n * 2 * 4);
  float* adst = (float*)alloc((size_t)n * 2 * 4);
  u16*  x1bf = (u16*)alloc((size_t)n * 128 * 2);      // bf16 x1
  float* qq   = (float*)alloc((size_t)n * 64 * 4);
  u16*  kk2  = (u16*)alloc((size_t)n * 64 * 2);       // bf16 k
  u16*  vv2  = (u16*)alloc((size_t)n * 64 * 2);       // bf16 v
  float* skip = (float*)alloc((size_t)n * 64 * 4);
  int* counts  = (int*)alloc((size_t)n * 4);
  int* offsets = (int*)alloc((size_t)(n + 1) * 4);
  int* csr     = (int*)alloc((size_t)E * 4);
  float* scw   = (float*)alloc((size_t)E * 4);

  // CSR build (dst-grouped)
  hipMemsetAsync(counts, 0, (size_t)n * 4, stream);
  count_deg_kernel<<<(E + 255) / 256, 256, 0, stream>>>(dst, counts, E);
  scan_kernel<<<1, 1024, 0, stream>>>(counts, offsets, n);
  hipMemcpyAsync(counts, offsets, (size_t)n * 4, hipMemcpyDeviceToDevice, stream);
  fill_csr_kernel<<<(E + 255) / 256, 256, 0, stream>>>(src, dst, counts, csr, E);

  // GAT layer
  gemm1_kernel<<<(n + 15) / 16, 256, 0, stream>>>(x, W1, h2, n);
  attn_coef_kernel<<<(n + 3) / 4, 256, 0, stream>>>(h2, att_src, att_dst, asrc, adst, n);
  gat_agg_kernel<<<(n + 3) / 4, 256, 0, stream>>>(h2, asrc, adst, offsets, csr, b1, x1bf, n);

  // Transformer layer
  gemm2_kernel<<<(n + 15) / 16, 256, 0, stream>>>(x1bf, Wq, Wk, Wv, Ws, bq, bk, bv, bs,
                                                  qq, kk2, vv2, skip, n);
  trans_agg_kernel<<<(n + 3) / 4, 256, 0, stream>>>(qq, kk2, vv2, skip, offsets, csr,
                                                    out, scw, n);
}

// Round 3
// 366.826 us; speedup vs baseline: 1.1546x; 1.1157x over previous
//
#include <hip/hip_runtime.h>
#include <math.h>

typedef unsigned short u16;
typedef unsigned int u32;

using bf16x8 = __attribute__((ext_vector_type(8))) short;
using f32x4  = __attribute__((ext_vector_type(4))) float;

__device__ __forceinline__ float lrelu02(float x){ return x > 0.f ? x : 0.2f * x; }

__device__ __forceinline__ float bf2f(u16 u){
  union { u32 i; float f; } v; v.i = ((u32)u) << 16; return v.f;
}
__device__ __forceinline__ u16 f2bf(float f){
  union { float ff; u32 i; } v; v.ff = f;
  u32 x = v.i;
  return (u16)((x + 0x7fffu + ((x >> 16) & 1u)) >> 16);  // RNE, no NaN inputs here
}
__device__ __forceinline__ u32 pack2(float lo, float hi){
  return (u32)f2bf(lo) | ((u32)f2bf(hi) << 16);
}

__device__ __forceinline__ float wave_max(float v){
#pragma unroll
  for (int o = 32; o > 0; o >>= 1) v = fmaxf(v, __shfl_xor(v, o));
  return v;
}
__device__ __forceinline__ float wave_sum(float v){
#pragma unroll
  for (int o = 32; o > 0; o >>= 1) v += __shfl_xor(v, o);
  return v;
}

// ---------------- prep: cast x (f32) -> bf16 ----------------
__global__ __launch_bounds__(256) void cast_x_kernel(const float* __restrict__ x,
                                                     u16* __restrict__ xbf, int total8){
  int i = blockIdx.x * 256 + threadIdx.x;
  if (i >= total8) return;
  const float4* x4 = (const float4*)x;
  float4 a = x4[(size_t)i * 2];
  float4 b = x4[(size_t)i * 2 + 1];
  uint4 w;
  w.x = pack2(a.x, a.y);
  w.y = pack2(a.z, a.w);
  w.z = pack2(b.x, b.y);
  w.w = pack2(b.z, b.w);
  ((uint4*)xbf)[i] = w;
}

// ---------------- prep: transpose weights to bf16 [col][k] ----------------
// w1t[j][k] = W1[k][j]  (128x128);  wt2[mat*64+j][k] = Wmat[k][j] (256x128)
__global__ __launch_bounds__(256) void prep_w_kernel(const float* __restrict__ W1,
                                                     const float* __restrict__ Wq,
                                                     const float* __restrict__ Wk,
                                                     const float* __restrict__ Wv,
                                                     const float* __restrict__ Ws,
                                                     u16* __restrict__ w1t,
                                                     u16* __restrict__ wt2){
  int idx = blockIdx.x * 256 + threadIdx.x;
  if (idx < 16384){
    int j = idx >> 7, k = idx & 127;
    w1t[j * 128 + k] = f2bf(W1[k * 128 + j]);
  } else if (idx < 49152){
    int i = idx - 16384;
    int mat = i >> 13;
    int r = i & 8191;
    int j = r >> 7, k = r & 127;
    const float* W = (mat == 0) ? Wq : (mat == 1) ? Wk : (mat == 2) ? Wv : Ws;
    wt2[(mat * 64 + j) * 128 + k] = f2bf(W[k * 64 + j]);
  }
}

// ---------------- GEMM1 (MFMA): h2[n][128](bf16) = xbf @ W1 ----------------
__global__ __launch_bounds__(256) void gemm1_mfma(const u16* __restrict__ xbf,
                                                  const u16* __restrict__ w1t,
                                                  u16* __restrict__ h2, int n){
  int wid = threadIdx.x >> 6, lane = threadIdx.x & 63;
  int rl = lane & 15, kh = lane >> 4;
  int br = blockIdx.x * 64 + wid * 16;
  int arow = br + rl; if (arow > n - 1) arow = n - 1;
  const u16* abase = xbf + (size_t)arow * 128 + kh * 8;
  f32x4 acc[8];
#pragma unroll
  for (int t = 0; t < 8; t++) acc[t] = (f32x4){0.f, 0.f, 0.f, 0.f};
#pragma unroll
  for (int ks = 0; ks < 4; ks++){
    bf16x8 a = *(const bf16x8*)(abase + ks * 32);
#pragma unroll
    for (int t = 0; t < 8; t++){
      bf16x8 b = *(const bf16x8*)(w1t + (size_t)(t * 16 + rl) * 128 + ks * 32 + kh * 8);
      acc[t] = __builtin_amdgcn_mfma_f32_16x16x32_bf16(a, b, acc[t], 0, 0, 0);
    }
  }
  int orow0 = br + kh * 4;
#pragma unroll
  for (int r = 0; r < 4; r++){
    int orow = orow0 + r;
    if (orow < n){
      u16* hp = h2 + (size_t)orow * 128 + rl;
#pragma unroll
      for (int t = 0; t < 8; t++) hp[t * 16] = f2bf(acc[t][r]);
    }
  }
}

// ------- GEMM2 (MFMA): {q,k,v,skip} = x1bf @ {Wq,Wk,Wv,Ws} + biases -------
__global__ __launch_bounds__(256) void gemm2_mfma(const u16* __restrict__ x1bf,
                                                  const u16* __restrict__ wt2,
                                                  const float* __restrict__ bq,
                                                  const float* __restrict__ bk,
                                                  const float* __restrict__ bv,
                                                  const float* __restrict__ bs,
                                                  float* __restrict__ q,
                                                  u16* __restrict__ k2,
                                                  u16* __restrict__ v2,
                                                  float* __restrict__ skip, int n){
  int wid = threadIdx.x >> 6, lane = threadIdx.x & 63;
  int rl = lane & 15, kh = lane >> 4;
  int br = blockIdx.x * 64 + wid * 16;
  int arow = br + rl; if (arow > n - 1) arow = n - 1;
  const u16* abase = x1bf + (size_t)arow * 128 + kh * 8;
  f32x4 acc[16];
#pragma unroll
  for (int t = 0; t < 16; t++) acc[t] = (f32x4){0.f, 0.f, 0.f, 0.f};
#pragma unroll
  for (int ks = 0; ks < 4; ks++){
    bf16x8 a = *(const bf16x8*)(abase + ks * 32);
#pragma unroll
    for (int t = 0; t < 16; t++){
      bf16x8 b = *(const bf16x8*)(wt2 + (size_t)(t * 16 + rl) * 128 + ks * 32 + kh * 8);
      acc[t] = __builtin_amdgcn_mfma_f32_16x16x32_bf16(a, b, acc[t], 0, 0, 0);
    }
  }
  float bias_t[16];
#pragma unroll
  for (int t = 0; t < 16; t++){
    const float* bb = (t < 4) ? bq : (t < 8) ? bk : (t < 12) ? bv : bs;
    bias_t[t] = bb[(t & 3) * 16 + rl];
  }
  int orow0 = br + kh * 4;
#pragma unroll
  for (int r = 0; r < 4; r++){
    int orow = orow0 + r;
    if (orow >= n) continue;
#pragma unroll
    for (int t = 0; t < 16; t++){
      int c = (t & 3) * 16 + rl;
      float val = acc[t][r] + bias_t[t];
      if (t < 4)       q[(size_t)orow * 64 + c]    = val;
      else if (t < 8)  k2[(size_t)orow * 64 + c]   = f2bf(val);
      else if (t < 12) v2[(size_t)orow * 64 + c]   = f2bf(val);
      else             skip[(size_t)orow * 64 + c] = val;
    }
  }
}

// -------- per-node attention coefficients: a_src/a_dst [n][2] --------
__global__ __launch_bounds__(256) void attn_coef_kernel(const u16* __restrict__ h2,
                                                        const float* __restrict__ att_src,
                                                        const float* __restrict__ att_dst,
                                                        float* __restrict__ asrc,
                                                        float* __restrict__ adst, int n){
  int node = blockIdx.x * 4 + (threadIdx.x >> 6);
  int lane = threadIdx.x & 63;
  if (node >= n) return;
  float h0 = bf2f(h2[(size_t)node * 128 + lane]);
  float h1 = bf2f(h2[(size_t)node * 128 + 64 + lane]);
  float as0 = wave_sum(h0 * att_src[lane]);
  float as1 = wave_sum(h1 * att_src[64 + lane]);
  float ad0 = wave_sum(h0 * att_dst[lane]);
  float ad1 = wave_sum(h1 * att_dst[64 + lane]);
  if (lane == 0){
    asrc[node * 2 + 0] = as0; asrc[node * 2 + 1] = as1;
    adst[node * 2 + 0] = ad0; adst[node * 2 + 1] = ad1;
  }
}

// ---------------- CSR build ----------------
__global__ __launch_bounds__(256) void count_deg_kernel(const int* __restrict__ dst,
                                                        int* __restrict__ counts, int E){
  int e = blockIdx.x * 256 + threadIdx.x;
  if (e < E) atomicAdd(&counts[dst[e]], 1);
}

__global__ __launch_bounds__(1024) void scan_kernel(const int* __restrict__ counts,
                                                    int* __restrict__ offsets, int n){
  __shared__ int buf[2][1024];
  int carry = 0;
  const int CH = 8192;
  for (int base = 0; base < n; base += CH){
    int local[8]; int lsum = 0;
#pragma unroll
    for (int j = 0; j < 8; j++){
      int i = base + threadIdx.x * 8 + j;
      int v = (i < n) ? counts[i] : 0;
      local[j] = lsum;
      lsum += v;
    }
    buf[0][threadIdx.x] = lsum;
    __syncthreads();
    int cur = 0;
    for (int off = 1; off < 1024; off <<= 1){
      int t = buf[cur][threadIdx.x];
      if ((int)threadIdx.x >= off) t += buf[cur][threadIdx.x - off];
      buf[cur ^ 1][threadIdx.x] = t;
      __syncthreads();
      cur ^= 1;
    }
    int excl = carry + (threadIdx.x > 0 ? buf[cur][threadIdx.x - 1] : 0);
#pragma unroll
    for (int j = 0; j < 8; j++){
      int i = base + threadIdx.x * 8 + j;
      if (i < n) offsets[i] = excl + local[j];
    }
    carry += buf[cur][1023];
    __syncthreads();
  }
  if (threadIdx.x == 0) offsets[n] = carry;
}

__global__ __launch_bounds__(256) void fill_csr_kernel(const int* __restrict__ src,
                                                       const int* __restrict__ dst,
                                                       int* __restrict__ cursor,
                                                       int* __restrict__ csr_src, int E){
  int e = blockIdx.x * 256 + threadIdx.x;
  if (e < E){
    int pos = atomicAdd(&cursor[dst[e]], 1);
    csr_src[pos] = src[e];
  }
}

// ---------------- GAT aggregation: one wave per node ----------------
__global__ __launch_bounds__(256) void gat_agg_kernel(const u16* __restrict__ h2,
                                                      const float* __restrict__ asrc,
                                                      const float* __restrict__ adst,
                                                      const int* __restrict__ off,
                                                      const int* __restrict__ csr_src,
                                                      const float* __restrict__ b1,
                                                      u16* __restrict__ x1bf, int n){
  int node = blockIdx.x * 4 + (threadIdx.x >> 6);
  int lane = threadIdx.x & 63;
  if (node >= n) return;
  int s0 = off[node];
  int d  = off[node + 1] - s0;
  float2 ad = ((const float2*)adst)[node];
  float2 asl = ((const float2*)asrc)[node];
  float e_self0 = lrelu02(asl.x + ad.x);
  float e_self1 = lrelu02(asl.y + ad.y);
  float m0 = e_self0, m1 = e_self1;
  for (int base = 0; base < d; base += 64){
    int idx = base + lane;
    bool valid = idx < d;
    int sj = valid ? csr_src[s0 + idx] : 0;
    float2 as = ((const float2*)asrc)[sj];
    float e0 = valid ? lrelu02(as.x + ad.x) : -3.0e38f;
    float e1 = valid ? lrelu02(as.y + ad.y) : -3.0e38f;
    m0 = fmaxf(m0, e0); m1 = fmaxf(m1, e1);
  }
  m0 = wave_max(m0); m1 = wave_max(m1);
  float pself0 = __expf(e_self0 - m0), pself1 = __expf(e_self1 - m1);
  float acc0 = pself0 * bf2f(h2[(size_t)node * 128 + lane]);
  float acc1 = pself1 * bf2f(h2[(size_t)node * 128 + 64 + lane]);
  float ps0 = 0.f, ps1 = 0.f;
  for (int base = 0; base < d; base += 64){
    int idx = base + lane;
    bool valid = idx < d;
    int sj = valid ? csr_src[s0 + idx] : 0;
    float2 as = ((const float2*)asrc)[sj];
    float p0 = valid ? __expf(lrelu02(as.x + ad.x) - m0) : 0.f;
    float p1 = valid ? __expf(lrelu02(as.y + ad.y) - m1) : 0.f;
    ps0 += p0; ps1 += p1;
    int cn = min(64, d - base);
#pragma unroll 4
    for (int j = 0; j < cn; j++){
      float a0 = __shfl(p0, j);
      float a1 = __shfl(p1, j);
      int sjj  = __shfl(sj, j);
      const u16* hr = h2 + (size_t)sjj * 128;
      acc0 = fmaf(a0, bf2f(hr[lane]), acc0);
      acc1 = fmaf(a1, bf2f(hr[64 + lane]), acc1);
    }
  }
  float s0t = pself0 + wave_sum(ps0);
  float s1t = pself1 + wave_sum(ps1);
  float v0 = acc0 / s0t + b1[lane];
  float v1 = acc1 / s1t + b1[64 + lane];
  x1bf[(size_t)node * 128 + lane]      = f2bf(fmaxf(v0, 0.f));
  x1bf[(size_t)node * 128 + 64 + lane] = f2bf(fmaxf(v1, 0.f));
}

// ---------- Transformer aggregation + log_softmax: one wave per node ----------
__global__ __launch_bounds__(256) void trans_agg_kernel(const float* __restrict__ q,
                                                        const u16* __restrict__ k2,
                                                        const u16* __restrict__ v2,
                                                        const float* __restrict__ skip,
                                                        const int* __restrict__ off,
                                                        const int* __restrict__ csr_src,
                                                        float* __restrict__ out,
                                                        float* __restrict__ score_ws, int n){
  int node = blockIdx.x * 4 + (threadIdx.x >> 6);
  int lane = threadIdx.x & 63;
  if (node >= n) return;
  int s0 = off[node];
  int d  = off[node + 1] - s0;
  int sub = lane & 3;
  const float* qp = q + (size_t)node * 64 + sub * 16;
  float4 qa = *(const float4*)(qp + 0);
  float4 qb = *(const float4*)(qp + 4);
  float4 qc = *(const float4*)(qp + 8);
  float4 qd = *(const float4*)(qp + 12);
  float m = -3.0e38f;
  for (int base = 0; base < d; base += 16){
    int eidx = base + (lane >> 2);
    bool valid = eidx < d;
    int sj = valid ? csr_src[s0 + eidx] : 0;
    const uint4* kp = (const uint4*)(k2 + (size_t)sj * 64 + sub * 16);
    uint4 ka = kp[0], kb = kp[1];
    float dot = 0.f;
    dot = fmaf(qa.x, bf2f((u16)(ka.x & 0xffffu)), dot);
    dot = fmaf(qa.y, bf2f((u16)(ka.x >> 16)), dot);
    dot = fmaf(qa.z, bf2f((u16)(ka.y & 0xffffu)), dot);
    dot = fmaf(qa.w, bf2f((u16)(ka.y >> 16)), dot);
    dot = fmaf(qb.x, bf2f((u16)(ka.z & 0xffffu)), dot);
    dot = fmaf(qb.y, bf2f((u16)(ka.z >> 16)), dot);
    dot = fmaf(qb.z, bf2f((u16)(ka.w & 0xffffu)), dot);
    dot = fmaf(qb.w, bf2f((u16)(ka.w >> 16)), dot);
    dot = fmaf(qc.x, bf2f((u16)(kb.x & 0xffffu)), dot);
    dot = fmaf(qc.y, bf2f((u16)(kb.x >> 16)), dot);
    dot = fmaf(qc.z, bf2f((u16)(kb.y & 0xffffu)), dot);
    dot = fmaf(qc.w, bf2f((u16)(kb.y >> 16)), dot);
    dot = fmaf(qd.x, bf2f((u16)(kb.z & 0xffffu)), dot);
    dot = fmaf(qd.y, bf2f((u16)(kb.z >> 16)), dot);
    dot = fmaf(qd.z, bf2f((u16)(kb.w & 0xffffu)), dot);
    dot = fmaf(qd.w, bf2f((u16)(kb.w >> 16)), dot);
    dot += __shfl_xor(dot, 1);
    dot += __shfl_xor(dot, 2);
    float sc = dot * 0.125f;
    if (valid && sub == 0) score_ws[s0 + eidx] = sc;
    m = fmaxf(m, valid ? sc : -3.0e38f);
  }
  m = wave_max(m);
  float ps = 0.f, acc = 0.f;
  for (int base = 0; base < d; base += 64){
    int idx = base + lane;
    bool valid = idx < d;
    int sj = valid ? csr_src[s0 + idx] : 0;
    float p = valid ? __expf(score_ws[s0 + idx] - m) : 0.f;
    ps += p;
    int cn = min(64, d - base);
#pragma unroll 4
    for (int j = 0; j < cn; j++){
      float a  = __shfl(p, j);
      int sjj  = __shfl(sj, j);
      acc = fmaf(a, bf2f(v2[(size_t)sjj * 64 + lane]), acc);
    }
  }
  ps = wave_sum(ps);
  float val = skip[(size_t)node * 64 + lane];
  if (d > 0) val += acc / ps;
  float mx = wave_max(val);
  float t  = val - mx;
  float se = wave_sum(__expf(t));
  out[(size_t)node * 64 + lane] = t - __logf(se);
}

extern "C" void kernel_launch(void* const* d_in, const int* in_sizes, int n_in,
                              void* d_out, int out_size, void* d_ws, size_t ws_size,
                              hipStream_t stream) {
  const float* x       = (const float*)d_in[0];
  const int*   ei      = (const int*)d_in[1];
  const float* W1      = (const float*)d_in[2];
  const float* att_src = (const float*)d_in[3];
  const float* att_dst = (const float*)d_in[4];
  const float* b1      = (const float*)d_in[5];
  const float* Wq = (const float*)d_in[6];  const float* bq = (const float*)d_in[7];
  const float* Wk = (const float*)d_in[8];  const float* bk = (const float*)d_in[9];
  const float* Wv = (const float*)d_in[10]; const float* bv = (const float*)d_in[11];
  const float* Ws = (const float*)d_in[12]; const float* bs = (const float*)d_in[13];
  float* out = (float*)d_out;

  int n = in_sizes[0] / 128;
  int E = in_sizes[1] / 2;
  const int* src = ei;
  const int* dst = ei + E;

  char* w = (char*)d_ws;
  auto alloc = [&](size_t bytes) -> void* {
    void* p = (void*)w;
    w += (bytes + 255) & ~(size_t)255;
    return p;
  };
  u16*  xbf  = (u16*)alloc((size_t)n * 128 * 2);      // bf16 x
  u16*  h2   = (u16*)alloc((size_t)n * 128 * 2);      // bf16 h
  float* asrc = (float*)alloc((size_t)n * 2 * 4);
  float* adst = (float*)alloc((size_t)n * 2 * 4);
  u16*  x1bf = (u16*)alloc((size_t)n * 128 * 2);      // bf16 x1
  float* qq   = (float*)alloc((size_t)n * 64 * 4);
  u16*  kk2  = (u16*)alloc((size_t)n * 64 * 2);       // bf16 k
  u16*  vv2  = (u16*)alloc((size_t)n * 64 * 2);       // bf16 v
  float* skip = (float*)alloc((size_t)n * 64 * 4);
  int* counts  = (int*)alloc((size_t)n * 4);
  int* offsets = (int*)alloc((size_t)(n + 1) * 4);
  int* csr     = (int*)alloc((size_t)E * 4);
  float* scw   = (float*)alloc((size_t)E * 4);
  u16*  w1t  = (u16*)alloc((size_t)128 * 128 * 2);    // bf16 W1^T
  u16*  wt2  = (u16*)alloc((size_t)256 * 128 * 2);    // bf16 [Wq|Wk|Wv|Ws]^T

  // prep (no deps)
  cast_x_kernel<<<(n * 16 + 255) / 256, 256, 0, stream>>>(x, xbf, n * 16);
  prep_w_kernel<<<192, 256, 0, stream>>>(W1, Wq, Wk, Wv, Ws, w1t, wt2);

  // CSR build (dst-grouped)
  hipMemsetAsync(counts, 0, (size_t)n * 4, stream);
  count_deg_kernel<<<(E + 255) / 256, 256, 0, stream>>>(dst, counts, E);
  scan_kernel<<<1, 1024, 0, stream>>>(counts, offsets, n);
  hipMemcpyAsync(counts, offsets, (size_t)n * 4, hipMemcpyDeviceToDevice, stream);
  fill_csr_kernel<<<(E + 255) / 256, 256, 0, stream>>>(src, dst, counts, csr, E);

  // GAT layer
  gemm1_mfma<<<(n + 63) / 64, 256, 0, stream>>>(xbf, w1t, h2, n);
  attn_coef_kernel<<<(n + 3) / 4, 256, 0, stream>>>(h2, att_src, att_dst, asrc, adst, n);
  gat_agg_kernel<<<(n + 3) / 4, 256, 0, stream>>>(h2, asrc, adst, offsets, csr, b1, x1bf, n);

  // Transformer layer
  gemm2_mfma<<<(n + 63) / 64, 256, 0, stream>>>(x1bf, wt2, bq, bk, bv, bs,
                                                qq, kk2, vv2, skip, n);
  trans_agg_kernel<<<(n + 3) / 4, 256, 0, stream>>>(qq, kk2, vv2, skip, offsets, csr,
                                                    out, scw, n);
}

// Round 4
// 319.167 us; speedup vs baseline: 1.3270x; 1.1493x over previous
//
#include <hip/hip_runtime.h>
#include <math.h>

typedef unsigned short u16;
typedef unsigned int u32;

using bf16x8 = __attribute__((ext_vector_type(8))) short;
using f32x4  = __attribute__((ext_vector_type(4))) float;

__device__ __forceinline__ float lrelu02(float x){ return x > 0.f ? x : 0.2f * x; }

__device__ __forceinline__ float bf2f(u16 u){
  union { u32 i; float f; } v; v.i = ((u32)u) << 16; return v.f;
}
__device__ __forceinline__ u16 f2bf(float f){
  union { float ff; u32 i; } v; v.ff = f;
  u32 x = v.i;
  return (u16)((x + 0x7fffu + ((x >> 16) & 1u)) >> 16);  // RNE
}
__device__ __forceinline__ u32 pack2(float lo, float hi){
  return (u32)f2bf(lo) | ((u32)f2bf(hi) << 16);
}

__device__ __forceinline__ float wave_max(float v){
#pragma unroll
  for (int o = 32; o > 0; o >>= 1) v = fmaxf(v, __shfl_xor(v, o));
  return v;
}
__device__ __forceinline__ float wave_sum(float v){
#pragma unroll
  for (int o = 32; o > 0; o >>= 1) v += __shfl_xor(v, o);
  return v;
}

// ---------------- prep: cast x (f32) -> bf16 ----------------
__global__ __launch_bounds__(256) void cast_x_kernel(const float* __restrict__ x,
                                                     u16* __restrict__ xbf, int total8){
  int i = blockIdx.x * 256 + threadIdx.x;
  if (i >= total8) return;
  const float4* x4 = (const float4*)x;
  float4 a = x4[(size_t)i * 2];
  float4 b = x4[(size_t)i * 2 + 1];
  uint4 w;
  w.x = pack2(a.x, a.y);
  w.y = pack2(a.z, a.w);
  w.z = pack2(b.x, b.y);
  w.w = pack2(b.z, b.w);
  ((uint4*)xbf)[i] = w;
}

// ---------------- prep: transpose weights to bf16 [col][k]; combined att cols ----------------
__global__ __launch_bounds__(256) void prep_w_kernel(const float* __restrict__ W1,
                                                     const float* __restrict__ Wq,
                                                     const float* __restrict__ Wk,
                                                     const float* __restrict__ Wv,
                                                     const float* __restrict__ Ws,
                                                     const float* __restrict__ att_src,
                                                     const float* __restrict__ att_dst,
                                                     u16* __restrict__ w1t,
                                                     u16* __restrict__ wt2,
                                                     u16* __restrict__ wxt){
  int idx = blockIdx.x * 256 + threadIdx.x;
  if (idx < 16384){
    int j = idx >> 7, k = idx & 127;
    w1t[j * 128 + k] = f2bf(W1[k * 128 + j]);
  } else if (idx < 49152){
    int i = idx - 16384;
    int mat = i >> 13;
    int r = i & 8191;
    int j = r >> 7, k = r & 127;
    const float* W = (mat == 0) ? Wq : (mat == 1) ? Wk : (mat == 2) ? Wv : Ws;
    wt2[(mat * 64 + j) * 128 + k] = f2bf(W[k * 64 + j]);
  } else if (idx < 49664){
    // wxt[j][k] = sum_c W1[k][head*64+c] * att[head][c];  j: 0=src h0,1=src h1,2=dst h0,3=dst h1
    int i = idx - 49152;
    int j = i >> 7, k = i & 127;
    const float* av = (j & 2) ? att_dst : att_src;
    int head = j & 1;
    float s = 0.f;
#pragma unroll 8
    for (int c = 0; c < 64; c++) s += W1[k * 128 + head * 64 + c] * av[head * 64 + c];
    wxt[j * 128 + k] = f2bf(s);
  } else if (idx < 51200){
    int i = idx - 49664;            // zero rows 4..15 of wxt
    wxt[512 + i] = 0;
  }
}

// ------- GEMM1 (MFMA): h2 = xbf @ W1 (bf16 out), fused a_src/a_dst epilogue -------
__global__ __launch_bounds__(256) void gemm1_mfma(const u16* __restrict__ xbf,
                                                  const u16* __restrict__ w1t,
                                                  const u16* __restrict__ wxt,
                                                  u16* __restrict__ h2,
                                                  float* __restrict__ asrc,
                                                  float* __restrict__ adst, int n){
  int wid = threadIdx.x >> 6, lane = threadIdx.x & 63;
  int rl = lane & 15, kh = lane >> 4;
  int br = blockIdx.x * 64 + wid * 16;
  int arow = br + rl; if (arow > n - 1) arow = n - 1;
  const u16* abase = xbf + (size_t)arow * 128 + kh * 8;
  f32x4 acc[9];
#pragma unroll
  for (int t = 0; t < 9; t++) acc[t] = (f32x4){0.f, 0.f, 0.f, 0.f};
#pragma unroll
  for (int ks = 0; ks < 4; ks++){
    bf16x8 a = *(const bf16x8*)(abase + ks * 32);
#pragma unroll
    for (int t = 0; t < 8; t++){
      bf16x8 b = *(const bf16x8*)(w1t + (size_t)(t * 16 + rl) * 128 + ks * 32 + kh * 8);
      acc[t] = __builtin_amdgcn_mfma_f32_16x16x32_bf16(a, b, acc[t], 0, 0, 0);
    }
    bf16x8 bx = *(const bf16x8*)(wxt + (size_t)rl * 128 + ks * 32 + kh * 8);
    acc[8] = __builtin_amdgcn_mfma_f32_16x16x32_bf16(a, bx, acc[8], 0, 0, 0);
  }
  int orow0 = br + kh * 4;
#pragma unroll
  for (int r = 0; r < 4; r++){
    int orow = orow0 + r;
    if (orow < n){
      u16* hp = h2 + (size_t)orow * 128 + rl;
#pragma unroll
      for (int t = 0; t < 8; t++) hp[t * 16] = f2bf(acc[t][r]);
      if (rl < 4){
        float vlv = acc[8][r];
        if (rl < 2) asrc[orow * 2 + rl] = vlv;
        else        adst[orow * 2 + (rl - 2)] = vlv;
      }
    }
  }
}

// ------- GEMM2 (MFMA): {q,k,v,skip} = x1bf @ {Wq,Wk,Wv,Ws} + biases -------
__global__ __launch_bounds__(256) void gemm2_mfma(const u16* __restrict__ x1bf,
                                                  const u16* __restrict__ wt2,
                                                  const float* __restrict__ bq,
                                                  const float* __restrict__ bk,
                                                  const float* __restrict__ bv,
                                                  const float* __restrict__ bs,
                                                  float* __restrict__ q,
                                                  u16* __restrict__ k2,
                                                  u16* __restrict__ v2,
                                                  float* __restrict__ skip, int n){
  int wid = threadIdx.x >> 6, lane = threadIdx.x & 63;
  int rl = lane & 15, kh = lane >> 4;
  int br = blockIdx.x * 64 + wid * 16;
  int arow = br + rl; if (arow > n - 1) arow = n - 1;
  const u16* abase = x1bf + (size_t)arow * 128 + kh * 8;
  f32x4 acc[16];
#pragma unroll
  for (int t = 0; t < 16; t++) acc[t] = (f32x4){0.f, 0.f, 0.f, 0.f};
#pragma unroll
  for (int ks = 0; ks < 4; ks++){
    bf16x8 a = *(const bf16x8*)(abase + ks * 32);
#pragma unroll
    for (int t = 0; t < 16; t++){
      bf16x8 b = *(const bf16x8*)(wt2 + (size_t)(t * 16 + rl) * 128 + ks * 32 + kh * 8);
      acc[t] = __builtin_amdgcn_mfma_f32_16x16x32_bf16(a, b, acc[t], 0, 0, 0);
    }
  }
  float bias_t[16];
#pragma unroll
  for (int t = 0; t < 16; t++){
    const float* bb = (t < 4) ? bq : (t < 8) ? bk : (t < 12) ? bv : bs;
    bias_t[t] = bb[(t & 3) * 16 + rl];
  }
  int orow0 = br + kh * 4;
#pragma unroll
  for (int r = 0; r < 4; r++){
    int orow = orow0 + r;
    if (orow >= n) continue;
#pragma unroll
    for (int t = 0; t < 16; t++){
      int c = (t & 3) * 16 + rl;
      float val = acc[t][r] + bias_t[t];
      if (t < 4)       q[(size_t)orow * 64 + c]    = val;
      else if (t < 8)  k2[(size_t)orow * 64 + c]   = f2bf(val);
      else if (t < 12) v2[(size_t)orow * 64 + c]   = f2bf(val);
      else             skip[(size_t)orow * 64 + c] = val;
    }
  }
}

// ---------------- CSR build ----------------
__global__ __launch_bounds__(256) void count_deg_kernel(const int* __restrict__ dst,
                                                        int* __restrict__ counts, int E){
  int e = blockIdx.x * 256 + threadIdx.x;
  if (e < E) atomicAdd(&counts[dst[e]], 1);
}

__global__ __launch_bounds__(1024) void scan_kernel(const int* __restrict__ counts,
                                                    int* __restrict__ offsets, int n){
  __shared__ int buf[2][1024];
  int carry = 0;
  const int CH = 8192;
  for (int base = 0; base < n; base += CH){
    int local[8]; int lsum = 0;
#pragma unroll
    for (int j = 0; j < 8; j++){
      int i = base + threadIdx.x * 8 + j;
      int v = (i < n) ? counts[i] : 0;
      local[j] = lsum;
      lsum += v;
    }
    buf[0][threadIdx.x] = lsum;
    __syncthreads();
    int cur = 0;
    for (int off = 1; off < 1024; off <<= 1){
      int t = buf[cur][threadIdx.x];
      if ((int)threadIdx.x >= off) t += buf[cur][threadIdx.x - off];
      buf[cur ^ 1][threadIdx.x] = t;
      __syncthreads();
      cur ^= 1;
    }
    int excl = carry + (threadIdx.x > 0 ? buf[cur][threadIdx.x - 1] : 0);
#pragma unroll
    for (int j = 0; j < 8; j++){
      int i = base + threadIdx.x * 8 + j;
      if (i < n) offsets[i] = excl + local[j];
    }
    carry += buf[cur][1023];
    __syncthreads();
  }
  if (threadIdx.x == 0) offsets[n] = carry;
}

__global__ __launch_bounds__(256) void fill_csr_kernel(const int* __restrict__ src,
                                                       const int* __restrict__ dst,
                                                       int* __restrict__ cursor,
                                                       int* __restrict__ csr_src, int E){
  int e = blockIdx.x * 256 + threadIdx.x;
  if (e < E){
    int pos = atomicAdd(&cursor[dst[e]], 1);
    csr_src[pos] = src[e];
  }
}

// ------------- GAT aggregation (fused, no max pass): one wave per node -------------
// 2 edges per iteration; 32 lanes per edge cover all 128 channels (4 each).
__global__ __launch_bounds__(256) void gat_agg_kernel(const u16* __restrict__ h2,
                                                      const float* __restrict__ asrc,
                                                      const float* __restrict__ adst,
                                                      const int* __restrict__ off,
                                                      const int* __restrict__ csr_src,
                                                      const float* __restrict__ b1,
                                                      u16* __restrict__ x1bf, int n){
  int node = blockIdx.x * 4 + (threadIdx.x >> 6);
  int lane = threadIdx.x & 63;
  if (node >= n) return;
  int s0 = off[node];
  int d  = off[node + 1] - s0;
  int g = lane >> 5;               // edge subgroup 0/1
  int l = lane & 31;
  int head = l >> 4;               // 0/1
  int chb = head * 64 + (l & 15) * 4;   // this lane's 4 channels
  float2 ad  = ((const float2*)adst)[node];
  float2 asl = ((const float2*)asrc)[node];
  float ad_own = head ? ad.y : ad.x;
  float pself = __expf(lrelu02((head ? asl.y : asl.x) + ad_own));
  float acc0 = 0.f, acc1 = 0.f, acc2 = 0.f, acc3 = 0.f, ps = 0.f;
#pragma unroll 4
  for (int base = 0; base < d; base += 2){
    int idx = base + g;
    bool valid = idx < d;
    int sj = csr_src[s0 + (valid ? idx : d - 1)];
    float2 as = ((const float2*)asrc)[sj];
    float p = valid ? __expf(lrelu02((head ? as.y : as.x) + ad_own)) : 0.f;
    ps += p;
    uint2 hv = *(const uint2*)(h2 + (size_t)sj * 128 + chb);
    acc0 = fmaf(p, bf2f((u16)(hv.x & 0xffffu)), acc0);
    acc1 = fmaf(p, bf2f((u16)(hv.x >> 16)), acc1);
    acc2 = fmaf(p, bf2f((u16)(hv.y & 0xffffu)), acc2);
    acc3 = fmaf(p, bf2f((u16)(hv.y >> 16)), acc3);
  }
  // reduce across the two edge subgroups (lane ^ 32 keeps head & channels)
  acc0 += __shfl_xor(acc0, 32);
  acc1 += __shfl_xor(acc1, 32);
  acc2 += __shfl_xor(acc2, 32);
  acc3 += __shfl_xor(acc3, 32);
  ps   += __shfl_xor(ps, 32);
  float st = ps + pself;
  uint2 hs = *(const uint2*)(h2 + (size_t)node * 128 + chb);
  acc0 = fmaf(pself, bf2f((u16)(hs.x & 0xffffu)), acc0);
  acc1 = fmaf(pself, bf2f((u16)(hs.x >> 16)), acc1);
  acc2 = fmaf(pself, bf2f((u16)(hs.y & 0xffffu)), acc2);
  acc3 = fmaf(pself, bf2f((u16)(hs.y >> 16)), acc3);
  float4 bv = *(const float4*)(b1 + chb);
  float inv = 1.f / st;
  float v0 = fmaxf(acc0 * inv + bv.x, 0.f);
  float v1 = fmaxf(acc1 * inv + bv.y, 0.f);
  float v2 = fmaxf(acc2 * inv + bv.z, 0.f);
  float v3 = fmaxf(acc3 * inv + bv.w, 0.f);
  if (lane < 32){
    uint2 wv; wv.x = pack2(v0, v1); wv.y = pack2(v2, v3);
    *(uint2*)(x1bf + (size_t)node * 128 + chb) = wv;
  }
}

// ------- Transformer aggregation (fused, no max pass) + log_softmax: one wave per node -------
// 4 edges per iteration; 16 lanes per edge cover 64 channels (4 each).
__global__ __launch_bounds__(256) void trans_agg_kernel(const float* __restrict__ q,
                                                        const u16* __restrict__ k2,
                                                        const u16* __restrict__ v2,
                                                        const float* __restrict__ skip,
                                                        const int* __restrict__ off,
                                                        const int* __restrict__ csr_src,
                                                        float* __restrict__ out, int n){
  int node = blockIdx.x * 4 + (threadIdx.x >> 6);
  int lane = threadIdx.x & 63;
  if (node >= n) return;
  int s0 = off[node];
  int d  = off[node + 1] - s0;
  int g = lane >> 4;               // edge subgroup 0..3
  int l = lane & 15;
  int chb = l * 4;                 // this lane's 4 channels
  float4 qv = *(const float4*)(q + (size_t)node * 64 + chb);
  float acc0 = 0.f, acc1 = 0.f, acc2 = 0.f, acc3 = 0.f, ps = 0.f;
#pragma unroll 4
  for (int base = 0; base < d; base += 4){
    int idx = base + g;
    bool valid = idx < d;
    int sj = csr_src[s0 + (valid ? idx : d - 1)];
    uint2 kv = *(const uint2*)(k2 + (size_t)sj * 64 + chb);
    float dot = qv.x * bf2f((u16)(kv.x & 0xffffu));
    dot = fmaf(qv.y, bf2f((u16)(kv.x >> 16)), dot);
    dot = fmaf(qv.z, bf2f((u16)(kv.y & 0xffffu)), dot);
    dot = fmaf(qv.w, bf2f((u16)(kv.y >> 16)), dot);
    dot += __shfl_xor(dot, 1);
    dot += __shfl_xor(dot, 2);
    dot += __shfl_xor(dot, 4);
    dot += __shfl_xor(dot, 8);
    float p = valid ? __expf(dot * 0.125f) : 0.f;
    ps += p;
    uint2 vv = *(const uint2*)(v2 + (size_t)sj * 64 + chb);
    acc0 = fmaf(p, bf2f((u16)(vv.x & 0xffffu)), acc0);
    acc1 = fmaf(p, bf2f((u16)(vv.x >> 16)), acc1);
    acc2 = fmaf(p, bf2f((u16)(vv.y & 0xffffu)), acc2);
    acc3 = fmaf(p, bf2f((u16)(vv.y >> 16)), acc3);
  }
  // reduce across the 4 edge subgroups (lane ^ 16, ^ 32 keep channel slot)
#pragma unroll
  for (int o = 16; o <= 32; o <<= 1){
    acc0 += __shfl_xor(acc0, o);
    acc1 += __shfl_xor(acc1, o);
    acc2 += __shfl_xor(acc2, o);
    acc3 += __shfl_xor(acc3, o);
    ps   += __shfl_xor(ps, o);
  }
  float4 sk = *(const float4*)(skip + (size_t)node * 64 + chb);
  float inv = (d > 0) ? 1.f / ps : 0.f;
  float v0 = sk.x + acc0 * inv;
  float v1 = sk.y + acc1 * inv;
  float v2f = sk.z + acc2 * inv;
  float v3 = sk.w + acc3 * inv;
  // log_softmax over 64 channels (each channel replicated over the 4 groups)
  float mx = wave_max(fmaxf(fmaxf(v0, v1), fmaxf(v2f, v3)));
  float t0 = v0 - mx, t1 = v1 - mx, t2 = v2f - mx, t3 = v3 - mx;
  float se = wave_sum(__expf(t0) + __expf(t1) + __expf(t2) + __expf(t3)) * 0.25f;
  float lse = __logf(se);
  if (lane < 16){
    float4 ov; ov.x = t0 - lse; ov.y = t1 - lse; ov.z = t2 - lse; ov.w = t3 - lse;
    *(float4*)(out + (size_t)node * 64 + chb) = ov;
  }
}

extern "C" void kernel_launch(void* const* d_in, const int* in_sizes, int n_in,
                              void* d_out, int out_size, void* d_ws, size_t ws_size,
                              hipStream_t stream) {
  const float* x       = (const float*)d_in[0];
  const int*   ei      = (const int*)d_in[1];
  const float* W1      = (const float*)d_in[2];
  const float* att_src = (const float*)d_in[3];
  const float* att_dst = (const float*)d_in[4];
  const float* b1      = (const float*)d_in[5];
  const float* Wq = (const float*)d_in[6];  const float* bq = (const float*)d_in[7];
  const float* Wk = (const float*)d_in[8];  const float* bk = (const float*)d_in[9];
  const float* Wv = (const float*)d_in[10]; const float* bv = (const float*)d_in[11];
  const float* Ws = (const float*)d_in[12]; const float* bs = (const float*)d_in[13];
  float* out = (float*)d_out;

  int n = in_sizes[0] / 128;
  int E = in_sizes[1] / 2;
  const int* src = ei;
  const int* dst = ei + E;

  char* w = (char*)d_ws;
  auto alloc = [&](size_t bytes) -> void* {
    void* p = (void*)w;
    w += (bytes + 255) & ~(size_t)255;
    return p;
  };
  u16*  xbf  = (u16*)alloc((size_t)n * 128 * 2);
  u16*  h2   = (u16*)alloc((size_t)n * 128 * 2);
  float* asrc = (float*)alloc((size_t)n * 2 * 4);
  float* adst = (float*)alloc((size_t)n * 2 * 4);
  u16*  x1bf = (u16*)alloc((size_t)n * 128 * 2);
  float* qq   = (float*)alloc((size_t)n * 64 * 4);
  u16*  kk2  = (u16*)alloc((size_t)n * 64 * 2);
  u16*  vv2  = (u16*)alloc((size_t)n * 64 * 2);
  float* skip = (float*)alloc((size_t)n * 64 * 4);
  int* counts  = (int*)alloc((size_t)n * 4);
  int* offsets = (int*)alloc((size_t)(n + 1) * 4);
  int* csr     = (int*)alloc((size_t)E * 4);
  u16*  w1t  = (u16*)alloc((size_t)128 * 128 * 2);
  u16*  wt2  = (u16*)alloc((size_t)256 * 128 * 2);
  u16*  wxt  = (u16*)alloc((size_t)16 * 128 * 2);

  // prep (no deps)
  cast_x_kernel<<<(n * 16 + 255) / 256, 256, 0, stream>>>(x, xbf, n * 16);
  prep_w_kernel<<<200, 256, 0, stream>>>(W1, Wq, Wk, Wv, Ws, att_src, att_dst,
                                         w1t, wt2, wxt);

  // CSR build (dst-grouped)
  hipMemsetAsync(counts, 0, (size_t)n * 4, stream);
  count_deg_kernel<<<(E + 255) / 256, 256, 0, stream>>>(dst, counts, E);
  scan_kernel<<<1, 1024, 0, stream>>>(counts, offsets, n);
  hipMemcpyAsync(counts, offsets, (size_t)n * 4, hipMemcpyDeviceToDevice, stream);
  fill_csr_kernel<<<(E + 255) / 256, 256, 0, stream>>>(src, dst, counts, csr, E);

  // GAT layer
  gemm1_mfma<<<(n + 63) / 64, 256, 0, stream>>>(xbf, w1t, wxt, h2, asrc, adst, n);
  gat_agg_kernel<<<(n + 3) / 4, 256, 0, stream>>>(h2, asrc, adst, offsets, csr, b1, x1bf, n);

  // Transformer layer
  gemm2_mfma<<<(n + 63) / 64, 256, 0, stream>>>(x1bf, wt2, bq, bk, bv, bs,
                                                qq, kk2, vv2, skip, n);
  trans_agg_kernel<<<(n + 3) / 4, 256, 0, stream>>>(qq, kk2, vv2, skip, offsets, csr,
                                                    out, n);
}

// Round 5
// 302.245 us; speedup vs baseline: 1.4013x; 1.0560x over previous
//
#include <hip/hip_runtime.h>
#include <math.h>

typedef unsigned short u16;
typedef unsigned int u32;

using bf16x8 = __attribute__((ext_vector_type(8))) short;
using f32x4  = __attribute__((ext_vector_type(4))) float;

__device__ __forceinline__ float lrelu02(float x){ return x > 0.f ? x : 0.2f * x; }

__device__ __forceinline__ float bf2f(u16 u){
  union { u32 i; float f; } v; v.i = ((u32)u) << 16; return v.f;
}
__device__ __forceinline__ u16 f2bf(float f){
  union { float ff; u32 i; } v; v.ff = f;
  u32 x = v.i;
  return (u16)((x + 0x7fffu + ((x >> 16) & 1u)) >> 16);  // RNE
}
__device__ __forceinline__ u32 pack2(float lo, float hi){
  return (u32)f2bf(lo) | ((u32)f2bf(hi) << 16);
}
__device__ __forceinline__ void unpack8(uint4 w, float* f){
  f[0] = bf2f((u16)(w.x & 0xffffu)); f[1] = bf2f((u16)(w.x >> 16));
  f[2] = bf2f((u16)(w.y & 0xffffu)); f[3] = bf2f((u16)(w.y >> 16));
  f[4] = bf2f((u16)(w.z & 0xffffu)); f[5] = bf2f((u16)(w.z >> 16));
  f[6] = bf2f((u16)(w.w & 0xffffu)); f[7] = bf2f((u16)(w.w >> 16));
}

// ---------------- prep: cast x (f32) -> bf16 ----------------
__global__ __launch_bounds__(256) void cast_x_kernel(const float* __restrict__ x,
                                                     u16* __restrict__ xbf, int total8){
  int i = blockIdx.x * 256 + threadIdx.x;
  if (i >= total8) return;
  const float4* x4 = (const float4*)x;
  float4 a = x4[(size_t)i * 2];
  float4 b = x4[(size_t)i * 2 + 1];
  uint4 w;
  w.x = pack2(a.x, a.y);
  w.y = pack2(a.z, a.w);
  w.z = pack2(b.x, b.y);
  w.w = pack2(b.z, b.w);
  ((uint4*)xbf)[i] = w;
}

// ---------------- prep: transpose weights to bf16 [col][k]; combined att cols ----------------
__global__ __launch_bounds__(256) void prep_w_kernel(const float* __restrict__ W1,
                                                     const float* __restrict__ Wq,
                                                     const float* __restrict__ Wk,
                                                     const float* __restrict__ Wv,
                                                     const float* __restrict__ Ws,
                                                     const float* __restrict__ att_src,
                                                     const float* __restrict__ att_dst,
                                                     u16* __restrict__ w1t,
                                                     u16* __restrict__ wt2,
                                                     u16* __restrict__ wxt){
  int idx = blockIdx.x * 256 + threadIdx.x;
  if (idx < 16384){
    int j = idx >> 7, k = idx & 127;
    w1t[j * 128 + k] = f2bf(W1[k * 128 + j]);
  } else if (idx < 49152){
    int i = idx - 16384;
    int mat = i >> 13;
    int r = i & 8191;
    int j = r >> 7, k = r & 127;
    const float* W = (mat == 0) ? Wq : (mat == 1) ? Wk : (mat == 2) ? Wv : Ws;
    wt2[(mat * 64 + j) * 128 + k] = f2bf(W[k * 64 + j]);
  } else if (idx < 49664){
    int i = idx - 49152;
    int j = i >> 7, k = i & 127;
    const float* av = (j & 2) ? att_dst : att_src;
    int head = j & 1;
    float s = 0.f;
#pragma unroll 8
    for (int c = 0; c < 64; c++) s += W1[k * 128 + head * 64 + c] * av[head * 64 + c];
    wxt[j * 128 + k] = f2bf(s);
  } else if (idx < 51200){
    int i = idx - 49664;            // zero rows 4..15 of wxt
    wxt[512 + i] = 0;
  }
}

// ------- GEMM1 (MFMA): h2 = xbf @ W1 (bf16 out), fused a_src/a_dst epilogue -------
__global__ __launch_bounds__(256) void gemm1_mfma(const u16* __restrict__ xbf,
                                                  const u16* __restrict__ w1t,
                                                  const u16* __restrict__ wxt,
                                                  u16* __restrict__ h2,
                                                  float* __restrict__ asrc,
                                                  float* __restrict__ adst, int n){
  int wid = threadIdx.x >> 6, lane = threadIdx.x & 63;
  int rl = lane & 15, kh = lane >> 4;
  int br = blockIdx.x * 64 + wid * 16;
  int arow = br + rl; if (arow > n - 1) arow = n - 1;
  const u16* abase = xbf + (size_t)arow * 128 + kh * 8;
  f32x4 acc[9];
#pragma unroll
  for (int t = 0; t < 9; t++) acc[t] = (f32x4){0.f, 0.f, 0.f, 0.f};
#pragma unroll
  for (int ks = 0; ks < 4; ks++){
    bf16x8 a = *(const bf16x8*)(abase + ks * 32);
#pragma unroll
    for (int t = 0; t < 8; t++){
      bf16x8 b = *(const bf16x8*)(w1t + (size_t)(t * 16 + rl) * 128 + ks * 32 + kh * 8);
      acc[t] = __builtin_amdgcn_mfma_f32_16x16x32_bf16(a, b, acc[t], 0, 0, 0);
    }
    bf16x8 bx = *(const bf16x8*)(wxt + (size_t)rl * 128 + ks * 32 + kh * 8);
    acc[8] = __builtin_amdgcn_mfma_f32_16x16x32_bf16(a, bx, acc[8], 0, 0, 0);
  }
  int orow0 = br + kh * 4;
#pragma unroll
  for (int r = 0; r < 4; r++){
    int orow = orow0 + r;
    if (orow < n){
      u16* hp = h2 + (size_t)orow * 128 + rl;
#pragma unroll
      for (int t = 0; t < 8; t++) hp[t * 16] = f2bf(acc[t][r]);
      if (rl < 4){
        float vlv = acc[8][r];
        if (rl < 2) asrc[orow * 2 + rl] = vlv;
        else        adst[orow * 2 + (rl - 2)] = vlv;
      }
    }
  }
}

// ------- GEMM2 (MFMA): {q, kv-interleaved, skip} = x1bf @ {Wq,Wk,Wv,Ws} + biases -------
__global__ __launch_bounds__(256) void gemm2_mfma(const u16* __restrict__ x1bf,
                                                  const u16* __restrict__ wt2,
                                                  const float* __restrict__ bq,
                                                  const float* __restrict__ bk,
                                                  const float* __restrict__ bv,
                                                  const float* __restrict__ bs,
                                                  float* __restrict__ q,
                                                  u16* __restrict__ kv2,
                                                  float* __restrict__ skip, int n){
  int wid = threadIdx.x >> 6, lane = threadIdx.x & 63;
  int rl = lane & 15, kh = lane >> 4;
  int br = blockIdx.x * 64 + wid * 16;
  int arow = br + rl; if (arow > n - 1) arow = n - 1;
  const u16* abase = x1bf + (size_t)arow * 128 + kh * 8;
  f32x4 acc[16];
#pragma unroll
  for (int t = 0; t < 16; t++) acc[t] = (f32x4){0.f, 0.f, 0.f, 0.f};
#pragma unroll
  for (int ks = 0; ks < 4; ks++){
    bf16x8 a = *(const bf16x8*)(abase + ks * 32);
#pragma unroll
    for (int t = 0; t < 16; t++){
      bf16x8 b = *(const bf16x8*)(wt2 + (size_t)(t * 16 + rl) * 128 + ks * 32 + kh * 8);
      acc[t] = __builtin_amdgcn_mfma_f32_16x16x32_bf16(a, b, acc[t], 0, 0, 0);
    }
  }
  float bias_t[16];
#pragma unroll
  for (int t = 0; t < 16; t++){
    const float* bb = (t < 4) ? bq : (t < 8) ? bk : (t < 12) ? bv : bs;
    bias_t[t] = bb[(t & 3) * 16 + rl];
  }
  int orow0 = br + kh * 4;
#pragma unroll
  for (int r = 0; r < 4; r++){
    int orow = orow0 + r;
    if (orow >= n) continue;
#pragma unroll
    for (int t = 0; t < 16; t++){
      int c = (t & 3) * 16 + rl;
      float val = acc[t][r] + bias_t[t];
      if (t < 4)       q[(size_t)orow * 64 + c]          = val;
      else if (t < 8)  kv2[(size_t)orow * 128 + c]       = f2bf(val);   // k half
      else if (t < 12) kv2[(size_t)orow * 128 + 64 + c]  = f2bf(val);   // v half
      else             skip[(size_t)orow * 64 + c]       = val;
    }
  }
}

// ---------------- CSR build ----------------
__global__ __launch_bounds__(256) void count_deg_kernel(const int* __restrict__ dst,
                                                        int* __restrict__ counts, int E){
  int e = blockIdx.x * 256 + threadIdx.x;
  if (e < E) atomicAdd(&counts[dst[e]], 1);
}

__global__ __launch_bounds__(1024) void scan_kernel(const int* __restrict__ counts,
                                                    int* __restrict__ offsets, int n){
  __shared__ int wsum[16];
  __shared__ int wpre[17];
  int carry = 0;
  const int CH = 8192;
  int wid = threadIdx.x >> 6, lane = threadIdx.x & 63;
  for (int base = 0; base < n; base += CH){
    int local[8]; int lsum = 0;
#pragma unroll
    for (int j = 0; j < 8; j++){
      int i = base + threadIdx.x * 8 + j;
      int v = (i < n) ? counts[i] : 0;
      local[j] = lsum;
      lsum += v;
    }
    int inc = lsum;
#pragma unroll
    for (int o = 1; o < 64; o <<= 1){
      int t = __shfl_up(inc, o);
      if (lane >= o) inc += t;
    }
    if (lane == 63) wsum[wid] = inc;
    __syncthreads();
    if (threadIdx.x == 0){
      int s = 0;
#pragma unroll
      for (int k2 = 0; k2 < 16; k2++){ wpre[k2] = s; s += wsum[k2]; }
      wpre[16] = s;
    }
    __syncthreads();
    int excl = carry + wpre[wid] + inc - lsum;
#pragma unroll
    for (int j = 0; j < 8; j++){
      int i = base + threadIdx.x * 8 + j;
      if (i < n) offsets[i] = excl + local[j];
    }
    carry += wpre[16];
    __syncthreads();
  }
  if (threadIdx.x == 0) offsets[n] = carry;
}

__global__ __launch_bounds__(256) void fill_csr_kernel(const int* __restrict__ src,
                                                       const int* __restrict__ dst,
                                                       int* __restrict__ cursor,
                                                       int* __restrict__ csr_src, int E){
  int e = blockIdx.x * 256 + threadIdx.x;
  if (e < E){
    int pos = atomicAdd(&cursor[dst[e]], 1);
    csr_src[pos] = src[e];
  }
}

// ------------- GAT aggregation: one wave per node, 4 edges/iter, 16 lanes/edge -------------
__global__ __launch_bounds__(256) void gat_agg_kernel(const u16* __restrict__ h2,
                                                      const float* __restrict__ asrc,
                                                      const float* __restrict__ adst,
                                                      const int* __restrict__ off,
                                                      const int* __restrict__ csr_src,
                                                      const float* __restrict__ b1,
                                                      u16* __restrict__ x1bf, int n){
  int node = blockIdx.x * 4 + (threadIdx.x >> 6);
  int lane = threadIdx.x & 63;
  if (node >= n) return;
  int s0 = off[node];
  int d  = off[node + 1] - s0;
  int g = lane >> 4;               // edge subgroup 0..3
  int l = lane & 15;
  int chb = l * 8;                 // this lane's 8 channels (0..120)
  int head = l >> 3;               // 0 for ch<64, 1 for ch>=64
  float2 ad  = ((const float2*)adst)[node];
  float2 asl = ((const float2*)asrc)[node];
  float ad_own = head ? ad.y : ad.x;
  float pself = __expf(lrelu02((head ? asl.y : asl.x) + ad_own));
  float acc[8];
#pragma unroll
  for (int i = 0; i < 8; i++) acc[i] = 0.f;
  float ps = 0.f;
#pragma unroll 2
  for (int base = 0; base < d; base += 4){
    int idx = base + g;
    bool valid = idx < d;
    int sj = csr_src[s0 + (valid ? idx : d - 1)];
    float2 as = ((const float2*)asrc)[sj];
    float p = valid ? __expf(lrelu02((head ? as.y : as.x) + ad_own)) : 0.f;
    ps += p;
    uint4 hv = *(const uint4*)(h2 + (size_t)sj * 128 + chb);
    float f[8]; unpack8(hv, f);
#pragma unroll
    for (int i = 0; i < 8; i++) acc[i] = fmaf(p, f[i], acc[i]);
  }
  // reduce across the 4 edge subgroups (keeps lane&15 -> channels & head)
#pragma unroll
  for (int o = 16; o <= 32; o <<= 1){
#pragma unroll
    for (int i = 0; i < 8; i++) acc[i] += __shfl_xor(acc[i], o);
    ps += __shfl_xor(ps, o);
  }
  if (lane < 16){
    float st = ps + pself;
    uint4 hs = *(const uint4*)(h2 + (size_t)node * 128 + chb);
    float f[8]; unpack8(hs, f);
    float4 b0 = *(const float4*)(b1 + chb);
    float4 b4 = *(const float4*)(b1 + chb + 4);
    float bb[8] = {b0.x, b0.y, b0.z, b0.w, b4.x, b4.y, b4.z, b4.w};
    float inv = 1.f / st;
    u32 wv[4];
#pragma unroll
    for (int i = 0; i < 4; i++){
      float v0 = fmaxf(fmaf(pself, f[2*i],   acc[2*i])   * inv + bb[2*i],   0.f);
      float v1 = fmaxf(fmaf(pself, f[2*i+1], acc[2*i+1]) * inv + bb[2*i+1], 0.f);
      wv[i] = pack2(v0, v1);
    }
    uint4 wq = {wv[0], wv[1], wv[2], wv[3]};
    *(uint4*)(x1bf + (size_t)node * 128 + chb) = wq;
  }
}

// ------- Transformer aggregation + log_softmax: one wave per node, 4 edges/iter -------
// kv2 row = [k(64ch) | v(64ch)] bf16, 256B. 16 lanes/edge: lanes 0-7 k-dot, 8-15 v-acc.
__global__ __launch_bounds__(256) void trans_agg_kernel(const float* __restrict__ q,
                                                        const u16* __restrict__ kv2,
                                                        const float* __restrict__ skip,
                                                        const int* __restrict__ off,
                                                        const int* __restrict__ csr_src,
                                                        float* __restrict__ out, int n){
  int node = blockIdx.x * 4 + (threadIdx.x >> 6);
  int lane = threadIdx.x & 63;
  if (node >= n) return;
  int s0 = off[node];
  int d  = off[node + 1] - s0;
  int g = lane >> 4;               // edge subgroup 0..3
  int l = lane & 15;
  int c8 = (l & 7) * 8;            // 8-channel slice within k- or v-half
  // q slice (meaningful on k lanes; harmless elsewhere)
  const float* qp = q + (size_t)node * 64 + c8;
  float4 q0 = *(const float4*)(qp);
  float4 q4 = *(const float4*)(qp + 4);
  float qr[8] = {q0.x, q0.y, q0.z, q0.w, q4.x, q4.y, q4.z, q4.w};
  float acc[8];
#pragma unroll
  for (int i = 0; i < 8; i++) acc[i] = 0.f;
  float ps = 0.f;
#pragma unroll 2
  for (int base = 0; base < d; base += 4){
    int idx = base + g;
    bool valid = idx < d;
    int sj = csr_src[s0 + (valid ? idx : d - 1)];
    uint4 w = *(const uint4*)(kv2 + (size_t)sj * 128 + l * 8);
    float f[8]; unpack8(w, f);
    float part = 0.f;
#pragma unroll
    for (int i = 0; i < 8; i++) part = fmaf(qr[i], f[i], part);
    part += __shfl_xor(part, 1);
    part += __shfl_xor(part, 2);
    part += __shfl_xor(part, 4);
    float dsum = __shfl_xor(part, 8);   // v lanes receive the k-half dot
    float p = valid ? __expf(dsum * 0.125f) : 0.f;
    ps += p;
#pragma unroll
    for (int i = 0; i < 8; i++) acc[i] = fmaf(p, f[i], acc[i]);
  }
  // reduce across the 4 edge subgroups (keeps lane&15)
#pragma unroll
  for (int o = 16; o <= 32; o <<= 1){
#pragma unroll
    for (int i = 0; i < 8; i++) acc[i] += __shfl_xor(acc[i], o);
    ps += __shfl_xor(ps, o);
  }
  if (lane >= 8 && lane < 16){     // group 0's v lanes hold the totals
    const float* sp = skip + (size_t)node * 64 + c8;
    float4 s0v = *(const float4*)(sp);
    float4 s4v = *(const float4*)(sp + 4);
    float sk[8] = {s0v.x, s0v.y, s0v.z, s0v.w, s4v.x, s4v.y, s4v.z, s4v.w};
    float inv = (d > 0) ? 1.f / ps : 0.f;
    float val[8];
    float mx = -3.0e38f;
#pragma unroll
    for (int i = 0; i < 8; i++){ val[i] = sk[i] + acc[i] * inv; mx = fmaxf(mx, val[i]); }
    mx = fmaxf(mx, __shfl_xor(mx, 1));
    mx = fmaxf(mx, __shfl_xor(mx, 2));
    mx = fmaxf(mx, __shfl_xor(mx, 4));
    float se = 0.f;
#pragma unroll
    for (int i = 0; i < 8; i++){ val[i] -= mx; se += __expf(val[i]); }
    se += __shfl_xor(se, 1);
    se += __shfl_xor(se, 2);
    se += __shfl_xor(se, 4);
    float lse = __logf(se);
    float* op = out + (size_t)node * 64 + c8;
    float4 o0 = {val[0] - lse, val[1] - lse, val[2] - lse, val[3] - lse};
    float4 o4 = {val[4] - lse, val[5] - lse, val[6] - lse, val[7] - lse};
    *(float4*)(op)     = o0;
    *(float4*)(op + 4) = o4;
  }
}

extern "C" void kernel_launch(void* const* d_in, const int* in_sizes, int n_in,
                              void* d_out, int out_size, void* d_ws, size_t ws_size,
                              hipStream_t stream) {
  const float* x       = (const float*)d_in[0];
  const int*   ei      = (const int*)d_in[1];
  const float* W1      = (const float*)d_in[2];
  const float* att_src = (const float*)d_in[3];
  const float* att_dst = (const float*)d_in[4];
  const float* b1      = (const float*)d_in[5];
  const float* Wq = (const float*)d_in[6];  const float* bq = (const float*)d_in[7];
  const float* Wk = (const float*)d_in[8];  const float* bk = (const float*)d_in[9];
  const float* Wv = (const float*)d_in[10]; const float* bv = (const float*)d_in[11];
  const float* Ws = (const float*)d_in[12]; const float* bs = (const float*)d_in[13];
  float* out = (float*)d_out;

  int n = in_sizes[0] / 128;
  int E = in_sizes[1] / 2;
  const int* src = ei;
  const int* dst = ei + E;

  char* w = (char*)d_ws;
  auto alloc = [&](size_t bytes) -> void* {
    void* p = (void*)w;
    w += (bytes + 255) & ~(size_t)255;
    return p;
  };
  u16*  xbf  = (u16*)alloc((size_t)n * 128 * 2);
  u16*  h2   = (u16*)alloc((size_t)n * 128 * 2);
  float* asrc = (float*)alloc((size_t)n * 2 * 4);
  float* adst = (float*)alloc((size_t)n * 2 * 4);
  u16*  x1bf = (u16*)alloc((size_t)n * 128 * 2);
  float* qq   = (float*)alloc((size_t)n * 64 * 4);
  u16*  kv2  = (u16*)alloc((size_t)n * 128 * 2);    // interleaved [k|v] bf16
  float* skip = (float*)alloc((size_t)n * 64 * 4);
  int* counts  = (int*)alloc((size_t)n * 4);
  int* offsets = (int*)alloc((size_t)(n + 1) * 4);
  int* csr     = (int*)alloc((size_t)E * 4);
  u16*  w1t  = (u16*)alloc((size_t)128 * 128 * 2);
  u16*  wt2  = (u16*)alloc((size_t)256 * 128 * 2);
  u16*  wxt  = (u16*)alloc((size_t)16 * 128 * 2);

  // prep (no deps)
  cast_x_kernel<<<(n * 16 + 255) / 256, 256, 0, stream>>>(x, xbf, n * 16);
  prep_w_kernel<<<200, 256, 0, stream>>>(W1, Wq, Wk, Wv, Ws, att_src, att_dst,
                                         w1t, wt2, wxt);

  // CSR build (dst-grouped)
  hipMemsetAsync(counts, 0, (size_t)n * 4, stream);
  count_deg_kernel<<<(E + 255) / 256, 256, 0, stream>>>(dst, counts, E);
  scan_kernel<<<1, 1024, 0, stream>>>(counts, offsets, n);
  hipMemcpyAsync(counts, offsets, (size_t)n * 4, hipMemcpyDeviceToDevice, stream);
  fill_csr_kernel<<<(E + 255) / 256, 256, 0, stream>>>(src, dst, counts, csr, E);

  // GAT layer
  gemm1_mfma<<<(n + 63) / 64, 256, 0, stream>>>(xbf, w1t, wxt, h2, asrc, adst, n);
  gat_agg_kernel<<<(n + 3) / 4, 256, 0, stream>>>(h2, asrc, adst, offsets, csr, b1, x1bf, n);

  // Transformer layer
  gemm2_mfma<<<(n + 63) / 64, 256, 0, stream>>>(x1bf, wt2, bq, bk, bv, bs,
                                                qq, kv2, skip, n);
  trans_agg_kernel<<<(n + 3) / 4, 256, 0, stream>>>(qq, kv2, skip, offsets, csr,
                                                    out, n);
}

// Round 6
// 202.879 us; speedup vs baseline: 2.0876x; 1.4898x over previous
//
#include <hip/hip_runtime.h>
#include <math.h>

typedef unsigned short u16;
typedef unsigned int u32;

using bf16x8 = __attribute__((ext_vector_type(8))) short;
using f32x4  = __attribute__((ext_vector_type(4))) float;

__device__ __forceinline__ float lrelu02(float x){ return x > 0.f ? x : 0.2f * x; }

__device__ __forceinline__ float bf2f(u16 u){
  union { u32 i; float f; } v; v.i = ((u32)u) << 16; return v.f;
}
__device__ __forceinline__ u16 f2bf(float f){
  union { float ff; u32 i; } v; v.ff = f;
  u32 x = v.i;
  return (u16)((x + 0x7fffu + ((x >> 16) & 1u)) >> 16);  // RNE
}
__device__ __forceinline__ u32 pack2(float lo, float hi){
  return (u32)f2bf(lo) | ((u32)f2bf(hi) << 16);
}
__device__ __forceinline__ void unpack8(uint4 w, float* f){
  f[0] = bf2f((u16)(w.x & 0xffffu)); f[1] = bf2f((u16)(w.x >> 16));
  f[2] = bf2f((u16)(w.y & 0xffffu)); f[3] = bf2f((u16)(w.y >> 16));
  f[4] = bf2f((u16)(w.z & 0xffffu)); f[5] = bf2f((u16)(w.z >> 16));
  f[6] = bf2f((u16)(w.w & 0xffffu)); f[7] = bf2f((u16)(w.w >> 16));
}

// ---------------- prep: cast x (f32) -> bf16 ----------------
__global__ __launch_bounds__(256) void cast_x_kernel(const float* __restrict__ x,
                                                     u16* __restrict__ xbf, int total8){
  int i = blockIdx.x * 256 + threadIdx.x;
  if (i >= total8) return;
  const float4* x4 = (const float4*)x;
  float4 a = x4[(size_t)i * 2];
  float4 b = x4[(size_t)i * 2 + 1];
  uint4 w;
  w.x = pack2(a.x, a.y);
  w.y = pack2(a.z, a.w);
  w.z = pack2(b.x, b.y);
  w.w = pack2(b.z, b.w);
  ((uint4*)xbf)[i] = w;
}

// ---------------- prep: transpose weights to bf16 [col][k]; combined att cols ----------------
__global__ __launch_bounds__(256) void prep_w_kernel(const float* __restrict__ W1,
                                                     const float* __restrict__ Wq,
                                                     const float* __restrict__ Wk,
                                                     const float* __restrict__ Wv,
                                                     const float* __restrict__ Ws,
                                                     const float* __restrict__ att_src,
                                                     const float* __restrict__ att_dst,
                                                     u16* __restrict__ w1t,
                                                     u16* __restrict__ wt2,
                                                     u16* __restrict__ wxt){
  int idx = blockIdx.x * 256 + threadIdx.x;
  if (idx < 16384){
    int j = idx >> 7, k = idx & 127;
    w1t[j * 128 + k] = f2bf(W1[k * 128 + j]);
  } else if (idx < 49152){
    int i = idx - 16384;
    int mat = i >> 13;
    int r = i & 8191;
    int j = r >> 7, k = r & 127;
    const float* W = (mat == 0) ? Wq : (mat == 1) ? Wk : (mat == 2) ? Wv : Ws;
    wt2[(mat * 64 + j) * 128 + k] = f2bf(W[k * 64 + j]);
  } else if (idx < 49664){
    int i = idx - 49152;
    int j = i >> 7, k = i & 127;
    const float* av = (j & 2) ? att_dst : att_src;
    int head = j & 1;
    float s = 0.f;
#pragma unroll 8
    for (int c = 0; c < 64; c++) s += W1[k * 128 + head * 64 + c] * av[head * 64 + c];
    wxt[j * 128 + k] = f2bf(s);
  } else if (idx < 51200){
    int i = idx - 49664;            // zero rows 4..15 of wxt
    wxt[512 + i] = 0;
  }
}

// ------- GEMM1 (MFMA): h2 = xbf @ W1 (bf16 out), fused a_src/a_dst epilogue -------
__global__ __launch_bounds__(256) void gemm1_mfma(const u16* __restrict__ xbf,
                                                  const u16* __restrict__ w1t,
                                                  const u16* __restrict__ wxt,
                                                  u16* __restrict__ h2,
                                                  float* __restrict__ asrc,
                                                  float* __restrict__ adst, int n){
  int wid = threadIdx.x >> 6, lane = threadIdx.x & 63;
  int rl = lane & 15, kh = lane >> 4;
  int br = blockIdx.x * 64 + wid * 16;
  int arow = br + rl; if (arow > n - 1) arow = n - 1;
  const u16* abase = xbf + (size_t)arow * 128 + kh * 8;
  f32x4 acc[9];
#pragma unroll
  for (int t = 0; t < 9; t++) acc[t] = (f32x4){0.f, 0.f, 0.f, 0.f};
#pragma unroll
  for (int ks = 0; ks < 4; ks++){
    bf16x8 a = *(const bf16x8*)(abase + ks * 32);
#pragma unroll
    for (int t = 0; t < 8; t++){
      bf16x8 b = *(const bf16x8*)(w1t + (size_t)(t * 16 + rl) * 128 + ks * 32 + kh * 8);
      acc[t] = __builtin_amdgcn_mfma_f32_16x16x32_bf16(a, b, acc[t], 0, 0, 0);
    }
    bf16x8 bx = *(const bf16x8*)(wxt + (size_t)rl * 128 + ks * 32 + kh * 8);
    acc[8] = __builtin_amdgcn_mfma_f32_16x16x32_bf16(a, bx, acc[8], 0, 0, 0);
  }
  int orow0 = br + kh * 4;
#pragma unroll
  for (int r = 0; r < 4; r++){
    int orow = orow0 + r;
    if (orow < n){
      u16* hp = h2 + (size_t)orow * 128 + rl;
#pragma unroll
      for (int t = 0; t < 8; t++) hp[t * 16] = f2bf(acc[t][r]);
      if (rl < 4){
        float vlv = acc[8][r];
        if (rl < 2) asrc[orow * 2 + rl] = vlv;
        else        adst[orow * 2 + (rl - 2)] = vlv;
      }
    }
  }
}

// ------- GEMM2 (MFMA): {q, kv-interleaved, skip} = x1bf @ {Wq,Wk,Wv,Ws} + biases -------
__global__ __launch_bounds__(256) void gemm2_mfma(const u16* __restrict__ x1bf,
                                                  const u16* __restrict__ wt2,
                                                  const float* __restrict__ bq,
                                                  const float* __restrict__ bk,
                                                  const float* __restrict__ bv,
                                                  const float* __restrict__ bs,
                                                  float* __restrict__ q,
                                                  u16* __restrict__ kv2,
                                                  float* __restrict__ skip, int n){
  int wid = threadIdx.x >> 6, lane = threadIdx.x & 63;
  int rl = lane & 15, kh = lane >> 4;
  int br = blockIdx.x * 64 + wid * 16;
  int arow = br + rl; if (arow > n - 1) arow = n - 1;
  const u16* abase = x1bf + (size_t)arow * 128 + kh * 8;
  f32x4 acc[16];
#pragma unroll
  for (int t = 0; t < 16; t++) acc[t] = (f32x4){0.f, 0.f, 0.f, 0.f};
#pragma unroll
  for (int ks = 0; ks < 4; ks++){
    bf16x8 a = *(const bf16x8*)(abase + ks * 32);
#pragma unroll
    for (int t = 0; t < 16; t++){
      bf16x8 b = *(const bf16x8*)(wt2 + (size_t)(t * 16 + rl) * 128 + ks * 32 + kh * 8);
      acc[t] = __builtin_amdgcn_mfma_f32_16x16x32_bf16(a, b, acc[t], 0, 0, 0);
    }
  }
  float bias_t[16];
#pragma unroll
  for (int t = 0; t < 16; t++){
    const float* bb = (t < 4) ? bq : (t < 8) ? bk : (t < 12) ? bv : bs;
    bias_t[t] = bb[(t & 3) * 16 + rl];
  }
  int orow0 = br + kh * 4;
#pragma unroll
  for (int r = 0; r < 4; r++){
    int orow = orow0 + r;
    if (orow >= n) continue;
#pragma unroll
    for (int t = 0; t < 16; t++){
      int c = (t & 3) * 16 + rl;
      float val = acc[t][r] + bias_t[t];
      if (t < 4)       q[(size_t)orow * 64 + c]          = val;
      else if (t < 8)  kv2[(size_t)orow * 128 + c]       = f2bf(val);   // k half
      else if (t < 12) kv2[(size_t)orow * 128 + 64 + c]  = f2bf(val);   // v half
      else             skip[(size_t)orow * 64 + c]       = val;
    }
  }
}

// ================= CSR build via 2-level multisplit =================
// bucket = dst >> 7 (128 nodes per bucket); requires n <= 65536 (nb <= 512).

// K1: coarse bucket histogram (LDS-staged)
__global__ __launch_bounds__(256) void bucket_hist_kernel(const int* __restrict__ dst,
                                                          int* __restrict__ bc, int E){
  __shared__ int h[512];
  for (int i = threadIdx.x; i < 512; i += 256) h[i] = 0;
  __syncthreads();
  int base = blockIdx.x * 4096;
#pragma unroll
  for (int i = 0; i < 16; i++){
    int e = base + i * 256 + threadIdx.x;
    if (e < E) atomicAdd(&h[dst[e] >> 7], 1);
  }
  __syncthreads();
  for (int i = threadIdx.x; i < 512; i += 256)
    if (h[i]) atomicAdd(&bc[i], h[i]);
}

// K2: exclusive scan of 512 bucket counts -> bases + cursors
__global__ __launch_bounds__(256) void bucket_scan_kernel(const int* __restrict__ bc,
                                                          int* __restrict__ bbase,
                                                          int* __restrict__ bcur){
  __shared__ int tmp[5];
  int tid = threadIdx.x;
  int c0 = bc[2 * tid], c1 = bc[2 * tid + 1];
  int s = c0 + c1, incl = s;
  int lane = tid & 63, wid = tid >> 6;
#pragma unroll
  for (int o = 1; o < 64; o <<= 1){
    int t = __shfl_up(incl, o);
    if (lane >= o) incl += t;
  }
  if (lane == 63) tmp[wid] = incl;
  __syncthreads();
  if (tid == 0){
    int run = 0;
#pragma unroll
    for (int w2 = 0; w2 < 4; w2++){ int t = tmp[w2]; tmp[w2] = run; run += t; }
    tmp[4] = run;
  }
  __syncthreads();
  int excl = tmp[wid] + incl - s;
  bbase[2 * tid]     = excl;      bbase[2 * tid + 1] = excl + c0;
  bcur[2 * tid]      = excl;      bcur[2 * tid + 1]  = excl + c0;
  if (tid == 255) bbase[512] = tmp[4];
}

// K3: multisplit scatter of (src,dst) into bucket-grouped ebuf
__global__ __launch_bounds__(256) void multisplit_kernel(const int* __restrict__ src,
                                                         const int* __restrict__ dst,
                                                         int* __restrict__ bcur,
                                                         uint2* __restrict__ ebuf, int E){
  __shared__ int h[512];
  __shared__ int gb[512];
  __shared__ int cur[512];
  int tid = threadIdx.x;
  for (int i = tid; i < 512; i += 256){ h[i] = 0; cur[i] = 0; }
  __syncthreads();
  int base = blockIdx.x * 4096;
  int myd[16];
#pragma unroll
  for (int i = 0; i < 16; i++){
    int e = base + i * 256 + tid;
    myd[i] = (e < E) ? dst[e] : -1;
    if (myd[i] >= 0) atomicAdd(&h[myd[i] >> 7], 1);
  }
  __syncthreads();
  for (int i = tid; i < 512; i += 256){
    int c = h[i];
    gb[i] = c ? atomicAdd(&bcur[i], c) : 0;
  }
  __syncthreads();
#pragma unroll
  for (int i = 0; i < 16; i++){
    if (myd[i] >= 0){
      int e = base + i * 256 + tid;
      int b = myd[i] >> 7;
      int r = atomicAdd(&cur[b], 1);
      uint2 ed; ed.x = (u32)src[e]; ed.y = (u32)myd[i];
      ebuf[gb[b] + r] = ed;
    }
  }
}

// K4: per-bucket fine pass -> offsets + csr (all writes within an L2-resident window)
__global__ __launch_bounds__(256) void bucket_csr_kernel(const uint2* __restrict__ ebuf,
                                                         const int* __restrict__ bbase,
                                                         int* __restrict__ offsets,
                                                         int* __restrict__ csr,
                                                         int n, int E, int nb){
  __shared__ int deg[128];
  __shared__ int loff[128];
  __shared__ int cur[128];
  int b = blockIdx.x, tid = threadIdx.x;
  int base = bbase[b], end = bbase[b + 1];
  if (tid < 128) deg[tid] = 0;
  __syncthreads();
  for (int e = base + tid; e < end; e += 256)
    atomicAdd(&deg[ebuf[e].y & 127], 1);
  __syncthreads();
  if (tid < 64){
    int v0 = deg[2 * tid], v1 = deg[2 * tid + 1];
    int s = v0 + v1, incl = s;
#pragma unroll
    for (int o = 1; o < 64; o <<= 1){
      int t = __shfl_up(incl, o);
      if (tid >= o) incl += t;
    }
    int excl = incl - s;
    loff[2 * tid] = excl; loff[2 * tid + 1] = excl + v0;
  }
  __syncthreads();
  int node0 = b << 7;
  if (tid < 128){
    cur[tid] = loff[tid];
    int node = node0 + tid;
    if (node < n) offsets[node] = base + loff[tid];
  }
  if (b == nb - 1 && tid == 0) offsets[n] = E;
  __syncthreads();
  for (int e = base + tid; e < end; e += 256){
    uint2 ed = ebuf[e];
    int r = atomicAdd(&cur[ed.y & 127], 1);
    csr[base + r] = (int)ed.x;
  }
}

// ------------- GAT aggregation: one wave per node, 4 edges/iter, 16 lanes/edge -------------
__global__ __launch_bounds__(256) void gat_agg_kernel(const u16* __restrict__ h2,
                                                      const float* __restrict__ asrc,
                                                      const float* __restrict__ adst,
                                                      const int* __restrict__ off,
                                                      const int* __restrict__ csr_src,
                                                      const float* __restrict__ b1,
                                                      u16* __restrict__ x1bf, int n){
  int node = blockIdx.x * 4 + (threadIdx.x >> 6);
  int lane = threadIdx.x & 63;
  if (node >= n) return;
  int s0 = off[node];
  int d  = off[node + 1] - s0;
  int g = lane >> 4;               // edge subgroup 0..3
  int l = lane & 15;
  int chb = l * 8;                 // this lane's 8 channels (0..120)
  int head = l >> 3;               // 0 for ch<64, 1 for ch>=64
  float2 ad  = ((const float2*)adst)[node];
  float2 asl = ((const float2*)asrc)[node];
  float ad_own = head ? ad.y : ad.x;
  float pself = __expf(lrelu02((head ? asl.y : asl.x) + ad_own));
  float acc[8];
#pragma unroll
  for (int i = 0; i < 8; i++) acc[i] = 0.f;
  float ps = 0.f;
#pragma unroll 2
  for (int base = 0; base < d; base += 4){
    int idx = base + g;
    bool valid = idx < d;
    int sj = csr_src[s0 + (valid ? idx : d - 1)];
    float2 as = ((const float2*)asrc)[sj];
    float p = valid ? __expf(lrelu02((head ? as.y : as.x) + ad_own)) : 0.f;
    ps += p;
    uint4 hv = *(const uint4*)(h2 + (size_t)sj * 128 + chb);
    float f[8]; unpack8(hv, f);
#pragma unroll
    for (int i = 0; i < 8; i++) acc[i] = fmaf(p, f[i], acc[i]);
  }
#pragma unroll
  for (int o = 16; o <= 32; o <<= 1){
#pragma unroll
    for (int i = 0; i < 8; i++) acc[i] += __shfl_xor(acc[i], o);
    ps += __shfl_xor(ps, o);
  }
  if (lane < 16){
    float st = ps + pself;
    uint4 hs = *(const uint4*)(h2 + (size_t)node * 128 + chb);
    float f[8]; unpack8(hs, f);
    float4 b0 = *(const float4*)(b1 + chb);
    float4 b4 = *(const float4*)(b1 + chb + 4);
    float bb[8] = {b0.x, b0.y, b0.z, b0.w, b4.x, b4.y, b4.z, b4.w};
    float inv = 1.f / st;
    u32 wv[4];
#pragma unroll
    for (int i = 0; i < 4; i++){
      float v0 = fmaxf(fmaf(pself, f[2*i],   acc[2*i])   * inv + bb[2*i],   0.f);
      float v1 = fmaxf(fmaf(pself, f[2*i+1], acc[2*i+1]) * inv + bb[2*i+1], 0.f);
      wv[i] = pack2(v0, v1);
    }
    uint4 wq = {wv[0], wv[1], wv[2], wv[3]};
    *(uint4*)(x1bf + (size_t)node * 128 + chb) = wq;
  }
}

// ------- Transformer aggregation + log_softmax: one wave per node, 4 edges/iter -------
__global__ __launch_bounds__(256) void trans_agg_kernel(const float* __restrict__ q,
                                                        const u16* __restrict__ kv2,
                                                        const float* __restrict__ skip,
                                                        const int* __restrict__ off,
                                                        const int* __restrict__ csr_src,
                                                        float* __restrict__ out, int n){
  int node = blockIdx.x * 4 + (threadIdx.x >> 6);
  int lane = threadIdx.x & 63;
  if (node >= n) return;
  int s0 = off[node];
  int d  = off[node + 1] - s0;
  int g = lane >> 4;               // edge subgroup 0..3
  int l = lane & 15;
  int c8 = (l & 7) * 8;            // 8-channel slice within k- or v-half
  const float* qp = q + (size_t)node * 64 + c8;
  float4 q0 = *(const float4*)(qp);
  float4 q4 = *(const float4*)(qp + 4);
  float qr[8] = {q0.x, q0.y, q0.z, q0.w, q4.x, q4.y, q4.z, q4.w};
  float acc[8];
#pragma unroll
  for (int i = 0; i < 8; i++) acc[i] = 0.f;
  float ps = 0.f;
#pragma unroll 2
  for (int base = 0; base < d; base += 4){
    int idx = base + g;
    bool valid = idx < d;
    int sj = csr_src[s0 + (valid ? idx : d - 1)];
    uint4 w = *(const uint4*)(kv2 + (size_t)sj * 128 + l * 8);
    float f[8]; unpack8(w, f);
    float part = 0.f;
#pragma unroll
    for (int i = 0; i < 8; i++) part = fmaf(qr[i], f[i], part);
    part += __shfl_xor(part, 1);
    part += __shfl_xor(part, 2);
    part += __shfl_xor(part, 4);
    float dsum = __shfl_xor(part, 8);   // v lanes receive the k-half dot
    float p = valid ? __expf(dsum * 0.125f) : 0.f;
    ps += p;
#pragma unroll
    for (int i = 0; i < 8; i++) acc[i] = fmaf(p, f[i], acc[i]);
  }
#pragma unroll
  for (int o = 16; o <= 32; o <<= 1){
#pragma unroll
    for (int i = 0; i < 8; i++) acc[i] += __shfl_xor(acc[i], o);
    ps += __shfl_xor(ps, o);
  }
  if (lane >= 8 && lane < 16){     // group 0's v lanes hold the totals
    const float* sp = skip + (size_t)node * 64 + c8;
    float4 s0v = *(const float4*)(sp);
    float4 s4v = *(const float4*)(sp + 4);
    float sk[8] = {s0v.x, s0v.y, s0v.z, s0v.w, s4v.x, s4v.y, s4v.z, s4v.w};
    float inv = (d > 0) ? 1.f / ps : 0.f;
    float val[8];
    float mx = -3.0e38f;
#pragma unroll
    for (int i = 0; i < 8; i++){ val[i] = sk[i] + acc[i] * inv; mx = fmaxf(mx, val[i]); }
    mx = fmaxf(mx, __shfl_xor(mx, 1));
    mx = fmaxf(mx, __shfl_xor(mx, 2));
    mx = fmaxf(mx, __shfl_xor(mx, 4));
    float se = 0.f;
#pragma unroll
    for (int i = 0; i < 8; i++){ val[i] -= mx; se += __expf(val[i]); }
    se += __shfl_xor(se, 1);
    se += __shfl_xor(se, 2);
    se += __shfl_xor(se, 4);
    float lse = __logf(se);
    float* op = out + (size_t)node * 64 + c8;
    float4 o0 = {val[0] - lse, val[1] - lse, val[2] - lse, val[3] - lse};
    float4 o4 = {val[4] - lse, val[5] - lse, val[6] - lse, val[7] - lse};
    *(float4*)(op)     = o0;
    *(float4*)(op + 4) = o4;
  }
}

extern "C" void kernel_launch(void* const* d_in, const int* in_sizes, int n_in,
                              void* d_out, int out_size, void* d_ws, size_t ws_size,
                              hipStream_t stream) {
  const float* x       = (const float*)d_in[0];
  const int*   ei      = (const int*)d_in[1];
  const float* W1      = (const float*)d_in[2];
  const float* att_src = (const float*)d_in[3];
  const float* att_dst = (const float*)d_in[4];
  const float* b1      = (const float*)d_in[5];
  const float* Wq = (const float*)d_in[6];  const float* bq = (const float*)d_in[7];
  const float* Wk = (const float*)d_in[8];  const float* bk = (const float*)d_in[9];
  const float* Wv = (const float*)d_in[10]; const float* bv = (const float*)d_in[11];
  const float* Ws = (const float*)d_in[12]; const float* bs = (const float*)d_in[13];
  float* out = (float*)d_out;

  int n = in_sizes[0] / 128;
  int E = in_sizes[1] / 2;
  const int* src = ei;
  const int* dst = ei + E;
  int nb = (n + 127) >> 7;          // coarse buckets (<=512 for n<=65536)

  char* w = (char*)d_ws;
  auto alloc = [&](size_t bytes) -> void* {
    void* p = (void*)w;
    w += (bytes + 255) & ~(size_t)255;
    return p;
  };
  u16*  xbf  = (u16*)alloc((size_t)n * 128 * 2);    // bf16 x; reused as ebuf after gemm1
  u16*  h2   = (u16*)alloc((size_t)n * 128 * 2);
  float* asrc = (float*)alloc((size_t)n * 2 * 4);
  float* adst = (float*)alloc((size_t)n * 2 * 4);
  u16*  x1bf = (u16*)alloc((size_t)n * 128 * 2);
  float* qq   = (float*)alloc((size_t)n * 64 * 4);
  u16*  kv2  = (u16*)alloc((size_t)n * 128 * 2);    // interleaved [k|v] bf16
  float* skip = (float*)alloc((size_t)n * 64 * 4);
  int* offsets = (int*)alloc((size_t)(n + 1) * 4);
  int* csr     = (int*)alloc((size_t)E * 4);
  int* bc      = (int*)alloc(516 * 4);
  int* bbase   = (int*)alloc(516 * 4);
  int* bcur    = (int*)alloc(516 * 4);
  u16*  w1t  = (u16*)alloc((size_t)128 * 128 * 2);
  u16*  wt2  = (u16*)alloc((size_t)256 * 128 * 2);
  u16*  wxt  = (u16*)alloc((size_t)16 * 128 * 2);
  uint2* ebuf = (uint2*)xbf;                        // alias: xbf dead after gemm1

  int eblocks = (E + 4095) / 4096;

  // prep + GEMM1 (xbf consumed before ebuf aliasing)
  hipMemsetAsync(bc, 0, 513 * 4, stream);
  cast_x_kernel<<<(n * 16 + 255) / 256, 256, 0, stream>>>(x, xbf, n * 16);
  prep_w_kernel<<<200, 256, 0, stream>>>(W1, Wq, Wk, Wv, Ws, att_src, att_dst,
                                         w1t, wt2, wxt);
  gemm1_mfma<<<(n + 63) / 64, 256, 0, stream>>>(xbf, w1t, wxt, h2, asrc, adst, n);

  // CSR build via multisplit
  bucket_hist_kernel<<<eblocks, 256, 0, stream>>>(dst, bc, E);
  bucket_scan_kernel<<<1, 256, 0, stream>>>(bc, bbase, bcur);
  multisplit_kernel<<<eblocks, 256, 0, stream>>>(src, dst, bcur, ebuf, E);
  bucket_csr_kernel<<<nb, 256, 0, stream>>>(ebuf, bbase, offsets, csr, n, E, nb);

  // GAT aggregation
  gat_agg_kernel<<<(n + 3) / 4, 256, 0, stream>>>(h2, asrc, adst, offsets, csr, b1, x1bf, n);

  // Transformer layer
  gemm2_mfma<<<(n + 63) / 64, 256, 0, stream>>>(x1bf, wt2, bq, bk, bv, bs,
                                                qq, kv2, skip, n);
  trans_agg_kernel<<<(n + 3) / 4, 256, 0, stream>>>(qq, kv2, skip, offsets, csr,
                                                    out, n);
}

// Round 7
// 186.529 us; speedup vs baseline: 2.2706x; 1.0877x over previous
//
#include <hip/hip_runtime.h>
#include <math.h>

typedef unsigned short u16;
typedef unsigned int u32;
typedef unsigned char u8;

using bf16x8 = __attribute__((ext_vector_type(8))) short;
using f32x4  = __attribute__((ext_vector_type(4))) float;
typedef __attribute__((ext_vector_type(2))) float vf2;

__device__ __forceinline__ float lrelu02(float x){ return x > 0.f ? x : 0.2f * x; }

__device__ __forceinline__ float bf2f(u16 u){
  union { u32 i; float f; } v; v.i = ((u32)u) << 16; return v.f;
}
__device__ __forceinline__ u16 f2bf(float f){
  union { float ff; u32 i; } v; v.ff = f;
  u32 x = v.i;
  return (u16)((x + 0x7fffu + ((x >> 16) & 1u)) >> 16);  // RNE
}
__device__ __forceinline__ u32 pack2(float lo, float hi){
  return (u32)f2bf(lo) | ((u32)f2bf(hi) << 16);
}
__device__ __forceinline__ void unpack8(uint4 w, float* f){
  f[0] = bf2f((u16)(w.x & 0xffffu)); f[1] = bf2f((u16)(w.x >> 16));
  f[2] = bf2f((u16)(w.y & 0xffffu)); f[3] = bf2f((u16)(w.y >> 16));
  f[4] = bf2f((u16)(w.z & 0xffffu)); f[5] = bf2f((u16)(w.z >> 16));
  f[6] = bf2f((u16)(w.w & 0xffffu)); f[7] = bf2f((u16)(w.w >> 16));
}
__device__ __forceinline__ u8 f2fp8(float v){
  return (u8)(__builtin_amdgcn_cvt_pk_fp8_f32(v, v, 0, false) & 0xff);
}

// ---------------- prep: cast x (f32) -> bf16 ----------------
__global__ __launch_bounds__(256) void cast_x_kernel(const float* __restrict__ x,
                                                     u16* __restrict__ xbf, int total8){
  int i = blockIdx.x * 256 + threadIdx.x;
  if (i >= total8) return;
  const float4* x4 = (const float4*)x;
  float4 a = x4[(size_t)i * 2];
  float4 b = x4[(size_t)i * 2 + 1];
  uint4 w;
  w.x = pack2(a.x, a.y);
  w.y = pack2(a.z, a.w);
  w.z = pack2(b.x, b.y);
  w.w = pack2(b.z, b.w);
  ((uint4*)xbf)[i] = w;
}

// ---------------- prep: transpose weights to bf16 [col][k]; combined att cols ----------------
__global__ __launch_bounds__(256) void prep_w_kernel(const float* __restrict__ W1,
                                                     const float* __restrict__ Wq,
                                                     const float* __restrict__ Wk,
                                                     const float* __restrict__ Wv,
                                                     const float* __restrict__ Ws,
                                                     const float* __restrict__ att_src,
                                                     const float* __restrict__ att_dst,
                                                     u16* __restrict__ w1t,
                                                     u16* __restrict__ wt2,
                                                     u16* __restrict__ wxt){
  int idx = blockIdx.x * 256 + threadIdx.x;
  if (idx < 16384){
    int j = idx >> 7, k = idx & 127;
    w1t[j * 128 + k] = f2bf(W1[k * 128 + j]);
  } else if (idx < 49152){
    int i = idx - 16384;
    int mat = i >> 13;
    int r = i & 8191;
    int j = r >> 7, k = r & 127;
    const float* W = (mat == 0) ? Wq : (mat == 1) ? Wk : (mat == 2) ? Wv : Ws;
    wt2[(mat * 64 + j) * 128 + k] = f2bf(W[k * 64 + j]);
  } else if (idx < 49664){
    int i = idx - 49152;
    int j = i >> 7, k = i & 127;
    const float* av = (j & 2) ? att_dst : att_src;
    int head = j & 1;
    float s = 0.f;
#pragma unroll 8
    for (int c = 0; c < 64; c++) s += W1[k * 128 + head * 64 + c] * av[head * 64 + c];
    wxt[j * 128 + k] = f2bf(s);
  } else if (idx < 51200){
    int i = idx - 49664;            // zero rows 4..15 of wxt
    wxt[512 + i] = 0;
  }
}

// ------- GEMM1 (MFMA): h2 = xbf @ W1 (bf16 out), fused a_src/a_dst epilogue -------
__global__ __launch_bounds__(256) void gemm1_mfma(const u16* __restrict__ xbf,
                                                  const u16* __restrict__ w1t,
                                                  const u16* __restrict__ wxt,
                                                  u16* __restrict__ h2,
                                                  float* __restrict__ asrc,
                                                  float* __restrict__ adst, int n){
  int wid = threadIdx.x >> 6, lane = threadIdx.x & 63;
  int rl = lane & 15, kh = lane >> 4;
  int br = blockIdx.x * 64 + wid * 16;
  int arow = br + rl; if (arow > n - 1) arow = n - 1;
  const u16* abase = xbf + (size_t)arow * 128 + kh * 8;
  f32x4 acc[9];
#pragma unroll
  for (int t = 0; t < 9; t++) acc[t] = (f32x4){0.f, 0.f, 0.f, 0.f};
#pragma unroll
  for (int ks = 0; ks < 4; ks++){
    bf16x8 a = *(const bf16x8*)(abase + ks * 32);
#pragma unroll
    for (int t = 0; t < 8; t++){
      bf16x8 b = *(const bf16x8*)(w1t + (size_t)(t * 16 + rl) * 128 + ks * 32 + kh * 8);
      acc[t] = __builtin_amdgcn_mfma_f32_16x16x32_bf16(a, b, acc[t], 0, 0, 0);
    }
    bf16x8 bx = *(const bf16x8*)(wxt + (size_t)rl * 128 + ks * 32 + kh * 8);
    acc[8] = __builtin_amdgcn_mfma_f32_16x16x32_bf16(a, bx, acc[8], 0, 0, 0);
  }
  int orow0 = br + kh * 4;
#pragma unroll
  for (int r = 0; r < 4; r++){
    int orow = orow0 + r;
    if (orow < n){
      u16* hp = h2 + (size_t)orow * 128 + rl;
#pragma unroll
      for (int t = 0; t < 8; t++) hp[t * 16] = f2bf(acc[t][r]);
      if (rl < 4){
        float vlv = acc[8][r];
        if (rl < 2) asrc[orow * 2 + rl] = vlv;
        else        adst[orow * 2 + (rl - 2)] = vlv;
      }
    }
  }
}

// ------- GEMM2 (MFMA): {q, kv-fp8 chunk-interleaved, skip} = x1bf @ {Wq,Wk,Wv,Ws} + biases -------
// kv8 row (128B) = 8 chunks of 16B; chunk s = k[8s..8s+7] fp8 || v[8s..8s+7] fp8
__global__ __launch_bounds__(256) void gemm2_mfma(const u16* __restrict__ x1bf,
                                                  const u16* __restrict__ wt2,
                                                  const float* __restrict__ bq,
                                                  const float* __restrict__ bk,
                                                  const float* __restrict__ bv,
                                                  const float* __restrict__ bs,
                                                  float* __restrict__ q,
                                                  u8* __restrict__ kv8,
                                                  float* __restrict__ skip, int n){
  int wid = threadIdx.x >> 6, lane = threadIdx.x & 63;
  int rl = lane & 15, kh = lane >> 4;
  int br = blockIdx.x * 64 + wid * 16;
  int arow = br + rl; if (arow > n - 1) arow = n - 1;
  const u16* abase = x1bf + (size_t)arow * 128 + kh * 8;
  f32x4 acc[16];
#pragma unroll
  for (int t = 0; t < 16; t++) acc[t] = (f32x4){0.f, 0.f, 0.f, 0.f};
#pragma unroll
  for (int ks = 0; ks < 4; ks++){
    bf16x8 a = *(const bf16x8*)(abase + ks * 32);
#pragma unroll
    for (int t = 0; t < 16; t++){
      bf16x8 b = *(const bf16x8*)(wt2 + (size_t)(t * 16 + rl) * 128 + ks * 32 + kh * 8);
      acc[t] = __builtin_amdgcn_mfma_f32_16x16x32_bf16(a, b, acc[t], 0, 0, 0);
    }
  }
  float bias_t[16];
#pragma unroll
  for (int t = 0; t < 16; t++){
    const float* bb = (t < 4) ? bq : (t < 8) ? bk : (t < 12) ? bv : bs;
    bias_t[t] = bb[(t & 3) * 16 + rl];
  }
  int orow0 = br + kh * 4;
#pragma unroll
  for (int r = 0; r < 4; r++){
    int orow = orow0 + r;
    if (orow >= n) continue;
#pragma unroll
    for (int t = 0; t < 16; t++){
      int c = (t & 3) * 16 + rl;
      float val = acc[t][r] + bias_t[t];
      if (t < 4)       q[(size_t)orow * 64 + c]    = val;
      else if (t < 8)  kv8[(size_t)orow * 128 + (c >> 3) * 16 + (c & 7)]     = f2fp8(val);
      else if (t < 12) kv8[(size_t)orow * 128 + (c >> 3) * 16 + 8 + (c & 7)] = f2fp8(val);
      else             skip[(size_t)orow * 64 + c] = val;
    }
  }
}

// ================= CSR build via 2-level multisplit =================
__global__ __launch_bounds__(256) void bucket_hist_kernel(const int* __restrict__ dst,
                                                          int* __restrict__ bc, int E){
  __shared__ int h[512];
  for (int i = threadIdx.x; i < 512; i += 256) h[i] = 0;
  __syncthreads();
  int base = blockIdx.x * 4096;
#pragma unroll
  for (int i = 0; i < 16; i++){
    int e = base + i * 256 + threadIdx.x;
    if (e < E) atomicAdd(&h[dst[e] >> 7], 1);
  }
  __syncthreads();
  for (int i = threadIdx.x; i < 512; i += 256)
    if (h[i]) atomicAdd(&bc[i], h[i]);
}

__global__ __launch_bounds__(256) void bucket_scan_kernel(const int* __restrict__ bc,
                                                          int* __restrict__ bbase,
                                                          int* __restrict__ bcur){
  __shared__ int tmp[5];
  int tid = threadIdx.x;
  int c0 = bc[2 * tid], c1 = bc[2 * tid + 1];
  int s = c0 + c1, incl = s;
  int lane = tid & 63, wid = tid >> 6;
#pragma unroll
  for (int o = 1; o < 64; o <<= 1){
    int t = __shfl_up(incl, o);
    if (lane >= o) incl += t;
  }
  if (lane == 63) tmp[wid] = incl;
  __syncthreads();
  if (tid == 0){
    int run = 0;
#pragma unroll
    for (int w2 = 0; w2 < 4; w2++){ int t = tmp[w2]; tmp[w2] = run; run += t; }
    tmp[4] = run;
  }
  __syncthreads();
  int excl = tmp[wid] + incl - s;
  bbase[2 * tid]     = excl;      bbase[2 * tid + 1] = excl + c0;
  bcur[2 * tid]      = excl;      bcur[2 * tid + 1]  = excl + c0;
  if (tid == 255) bbase[512] = tmp[4];
}

__global__ __launch_bounds__(256) void multisplit_kernel(const int* __restrict__ src,
                                                         const int* __restrict__ dst,
                                                         int* __restrict__ bcur,
                                                         uint2* __restrict__ ebuf, int E){
  __shared__ int h[512];
  __shared__ int gb[512];
  __shared__ int cur[512];
  int tid = threadIdx.x;
  for (int i = tid; i < 512; i += 256){ h[i] = 0; cur[i] = 0; }
  __syncthreads();
  int base = blockIdx.x * 4096;
  int myd[16];
#pragma unroll
  for (int i = 0; i < 16; i++){
    int e = base + i * 256 + tid;
    myd[i] = (e < E) ? dst[e] : -1;
    if (myd[i] >= 0) atomicAdd(&h[myd[i] >> 7], 1);
  }
  __syncthreads();
  for (int i = tid; i < 512; i += 256){
    int c = h[i];
    gb[i] = c ? atomicAdd(&bcur[i], c) : 0;
  }
  __syncthreads();
#pragma unroll
  for (int i = 0; i < 16; i++){
    if (myd[i] >= 0){
      int e = base + i * 256 + tid;
      int b = myd[i] >> 7;
      int r = atomicAdd(&cur[b], 1);
      uint2 ed; ed.x = (u32)src[e]; ed.y = (u32)myd[i];
      ebuf[gb[b] + r] = ed;
    }
  }
}

__global__ __launch_bounds__(256) void bucket_csr_kernel(const uint2* __restrict__ ebuf,
                                                         const int* __restrict__ bbase,
                                                         int* __restrict__ offsets,
                                                         int* __restrict__ csr,
                                                         int n, int E, int nb){
  __shared__ int deg[128];
  __shared__ int loff[128];
  __shared__ int cur[128];
  int b = blockIdx.x, tid = threadIdx.x;
  int base = bbase[b], end = bbase[b + 1];
  if (tid < 128) deg[tid] = 0;
  __syncthreads();
  for (int e = base + tid; e < end; e += 256)
    atomicAdd(&deg[ebuf[e].y & 127], 1);
  __syncthreads();
  if (tid < 64){
    int v0 = deg[2 * tid], v1 = deg[2 * tid + 1];
    int s = v0 + v1, incl = s;
#pragma unroll
    for (int o = 1; o < 64; o <<= 1){
      int t = __shfl_up(incl, o);
      if (tid >= o) incl += t;
    }
    int excl = incl - s;
    loff[2 * tid] = excl; loff[2 * tid + 1] = excl + v0;
  }
  __syncthreads();
  int node0 = b << 7;
  if (tid < 128){
    cur[tid] = loff[tid];
    int node = node0 + tid;
    if (node < n) offsets[node] = base + loff[tid];
  }
  if (b == nb - 1 && tid == 0) offsets[n] = E;
  __syncthreads();
  for (int e = base + tid; e < end; e += 256){
    uint2 ed = ebuf[e];
    int r = atomicAdd(&cur[ed.y & 127], 1);
    csr[base + r] = (int)ed.x;
  }
}

// ------------- GAT aggregation: one wave per node, 8 edges/iter, 8 lanes/edge -------------
__global__ __launch_bounds__(256) void gat_agg_kernel(const u16* __restrict__ h2,
                                                      const float* __restrict__ asrc,
                                                      const float* __restrict__ adst,
                                                      const int* __restrict__ off,
                                                      const int* __restrict__ csr_src,
                                                      const float* __restrict__ b1,
                                                      u16* __restrict__ x1bf, int n){
  int node = blockIdx.x * 4 + (threadIdx.x >> 6);
  int lane = threadIdx.x & 63;
  if (node >= n) return;
  int s0 = off[node];
  int d  = off[node + 1] - s0;
  int g = lane >> 3;               // edge subgroup 0..7
  int sub = lane & 7;
  int chb = sub * 16;              // this lane's 16 channels
  int head = sub >> 2;             // 0 for ch<64, 1 for ch>=64
  float2 ad  = ((const float2*)adst)[node];
  float2 asl = ((const float2*)asrc)[node];
  float ad_own = head ? ad.y : ad.x;
  float pself = __expf(lrelu02((head ? asl.y : asl.x) + ad_own));
  float acc[16];
#pragma unroll
  for (int i = 0; i < 16; i++) acc[i] = 0.f;
  float ps = 0.f;
#pragma unroll 2
  for (int base = 0; base < d; base += 8){
    int idx = base + g;
    bool valid = idx < d;
    int sj = csr_src[s0 + (valid ? idx : d - 1)];
    float2 as = ((const float2*)asrc)[sj];
    float p = valid ? __expf(lrelu02((head ? as.y : as.x) + ad_own)) : 0.f;
    ps += p;
    const u16* hr = h2 + (size_t)sj * 128 + chb;
    uint4 ha = *(const uint4*)hr;
    uint4 hb = *(const uint4*)(hr + 8);
    float f[16];
    unpack8(ha, f); unpack8(hb, f + 8);
#pragma unroll
    for (int i = 0; i < 16; i++) acc[i] = fmaf(p, f[i], acc[i]);
  }
  // butterfly across the 8 edge subgroups (keeps lane&7 -> channel slot)
#pragma unroll
  for (int o = 8; o <= 32; o <<= 1){
#pragma unroll
    for (int i = 0; i < 16; i++) acc[i] += __shfl_xor(acc[i], o);
    ps += __shfl_xor(ps, o);
  }
  if (lane < 8){
    float st = ps + pself;
    const u16* hs = h2 + (size_t)node * 128 + chb;
    uint4 ha = *(const uint4*)hs;
    uint4 hb = *(const uint4*)(hs + 8);
    float f[16];
    unpack8(ha, f); unpack8(hb, f + 8);
    const float4* bp = (const float4*)(b1 + chb);
    float4 bv0 = bp[0], bv1 = bp[1], bv2 = bp[2], bv3 = bp[3];
    float bb[16] = {bv0.x, bv0.y, bv0.z, bv0.w, bv1.x, bv1.y, bv1.z, bv1.w,
                    bv2.x, bv2.y, bv2.z, bv2.w, bv3.x, bv3.y, bv3.z, bv3.w};
    float inv = 1.f / st;
    u32 wv[8];
#pragma unroll
    for (int i = 0; i < 8; i++){
      float v0 = fmaxf(fmaf(pself, f[2*i],   acc[2*i])   * inv + bb[2*i],   0.f);
      float v1 = fmaxf(fmaf(pself, f[2*i+1], acc[2*i+1]) * inv + bb[2*i+1], 0.f);
      wv[i] = pack2(v0, v1);
    }
    uint4 o0 = {wv[0], wv[1], wv[2], wv[3]};
    uint4 o1 = {wv[4], wv[5], wv[6], wv[7]};
    u16* xp = x1bf + (size_t)node * 128 + chb;
    *(uint4*)xp = o0;
    *(uint4*)(xp + 8) = o1;
  }
}

// ------- Transformer aggregation + log_softmax: one wave per node, 8 edges/iter -------
// kv8 row = 8 chunks of [k(8)|v(8)] fp8. Lane sub owns chunk sub: 8 k-ch for dot + 8 v-ch for acc.
__global__ __launch_bounds__(256) void trans_agg_kernel(const float* __restrict__ q,
                                                        const u8* __restrict__ kv8,
                                                        const float* __restrict__ skip,
                                                        const int* __restrict__ off,
                                                        const int* __restrict__ csr_src,
                                                        float* __restrict__ out, int n){
  int node = blockIdx.x * 4 + (threadIdx.x >> 6);
  int lane = threadIdx.x & 63;
  if (node >= n) return;
  int s0 = off[node];
  int d  = off[node + 1] - s0;
  int g = lane >> 3;               // edge subgroup 0..7
  int sub = lane & 7;              // chunk / channel-slot
  const float4* qp = (const float4*)(q + (size_t)node * 64 + sub * 8);
  float4 qa = qp[0], qb = qp[1];
  float acc[8];
#pragma unroll
  for (int i = 0; i < 8; i++) acc[i] = 0.f;
  float ps = 0.f;
#pragma unroll 2
  for (int base = 0; base < d; base += 8){
    int idx = base + g;
    bool valid = idx < d;
    int sj = csr_src[s0 + (valid ? idx : d - 1)];
    uint4 w = *(const uint4*)(kv8 + (size_t)sj * 128 + sub * 16);
    vf2 k0 = __builtin_amdgcn_cvt_pk_f32_fp8((int)w.x, false);
    vf2 k1 = __builtin_amdgcn_cvt_pk_f32_fp8((int)w.x, true);
    vf2 k2 = __builtin_amdgcn_cvt_pk_f32_fp8((int)w.y, false);
    vf2 k3 = __builtin_amdgcn_cvt_pk_f32_fp8((int)w.y, true);
    float part = qa.x * k0[0];
    part = fmaf(qa.y, k0[1], part);
    part = fmaf(qa.z, k1[0], part);
    part = fmaf(qa.w, k1[1], part);
    part = fmaf(qb.x, k2[0], part);
    part = fmaf(qb.y, k2[1], part);
    part = fmaf(qb.z, k3[0], part);
    part = fmaf(qb.w, k3[1], part);
    part += __shfl_xor(part, 1);
    part += __shfl_xor(part, 2);
    part += __shfl_xor(part, 4);
    float p = valid ? __expf(part * 0.125f) : 0.f;
    ps += p;
    vf2 v0 = __builtin_amdgcn_cvt_pk_f32_fp8((int)w.z, false);
    vf2 v1 = __builtin_amdgcn_cvt_pk_f32_fp8((int)w.z, true);
    vf2 v2 = __builtin_amdgcn_cvt_pk_f32_fp8((int)w.w, false);
    vf2 v3 = __builtin_amdgcn_cvt_pk_f32_fp8((int)w.w, true);
    acc[0] = fmaf(p, v0[0], acc[0]);
    acc[1] = fmaf(p, v0[1], acc[1]);
    acc[2] = fmaf(p, v1[0], acc[2]);
    acc[3] = fmaf(p, v1[1], acc[3]);
    acc[4] = fmaf(p, v2[0], acc[4]);
    acc[5] = fmaf(p, v2[1], acc[5]);
    acc[6] = fmaf(p, v3[0], acc[6]);
    acc[7] = fmaf(p, v3[1], acc[7]);
  }
  // butterfly across the 8 edge subgroups (keeps lane&7 -> channel slot)
#pragma unroll
  for (int o = 8; o <= 32; o <<= 1){
#pragma unroll
    for (int i = 0; i < 8; i++) acc[i] += __shfl_xor(acc[i], o);
    ps += __shfl_xor(ps, o);
  }
  if (lane < 8){
    const float4* sp = (const float4*)(skip + (size_t)node * 64 + sub * 8);
    float4 s0v = sp[0], s1v = sp[1];
    float sk[8] = {s0v.x, s0v.y, s0v.z, s0v.w, s1v.x, s1v.y, s1v.z, s1v.w};
    float inv = (d > 0) ? 1.f / ps : 0.f;
    float val[8];
    float mx = -3.0e38f;
#pragma unroll
    for (int i = 0; i < 8; i++){ val[i] = sk[i] + acc[i] * inv; mx = fmaxf(mx, val[i]); }
    mx = fmaxf(mx, __shfl_xor(mx, 1));
    mx = fmaxf(mx, __shfl_xor(mx, 2));
    mx = fmaxf(mx, __shfl_xor(mx, 4));
    float se = 0.f;
#pragma unroll
    for (int i = 0; i < 8; i++){ val[i] -= mx; se += __expf(val[i]); }
    se += __shfl_xor(se, 1);
    se += __shfl_xor(se, 2);
    se += __shfl_xor(se, 4);
    float lse = __logf(se);
    float* op = out + (size_t)node * 64 + sub * 8;
    float4 o0 = {val[0] - lse, val[1] - lse, val[2] - lse, val[3] - lse};
    float4 o4 = {val[4] - lse, val[5] - lse, val[6] - lse, val[7] - lse};
    *(float4*)(op)     = o0;
    *(float4*)(op + 4) = o4;
  }
}

extern "C" void kernel_launch(void* const* d_in, const int* in_sizes, int n_in,
                              void* d_out, int out_size, void* d_ws, size_t ws_size,
                              hipStream_t stream) {
  const float* x       = (const float*)d_in[0];
  const int*   ei      = (const int*)d_in[1];
  const float* W1      = (const float*)d_in[2];
  const float* att_src = (const float*)d_in[3];
  const float* att_dst = (const float*)d_in[4];
  const float* b1      = (const float*)d_in[5];
  const float* Wq = (const float*)d_in[6];  const float* bq = (const float*)d_in[7];
  const float* Wk = (const float*)d_in[8];  const float* bk = (const float*)d_in[9];
  const float* Wv = (const float*)d_in[10]; const float* bv = (const float*)d_in[11];
  const float* Ws = (const float*)d_in[12]; const float* bs = (const float*)d_in[13];
  float* out = (float*)d_out;

  int n = in_sizes[0] / 128;
  int E = in_sizes[1] / 2;
  const int* src = ei;
  const int* dst = ei + E;
  int nb = (n + 127) >> 7;          // coarse buckets (<=512 for n<=65536)

  char* w = (char*)d_ws;
  auto alloc = [&](size_t bytes) -> void* {
    void* p = (void*)w;
    w += (bytes + 255) & ~(size_t)255;
    return p;
  };
  u16*  xbf  = (u16*)alloc((size_t)n * 128 * 2);    // bf16 x; reused as ebuf after gemm1
  u16*  h2   = (u16*)alloc((size_t)n * 128 * 2);
  float* asrc = (float*)alloc((size_t)n * 2 * 4);
  float* adst = (float*)alloc((size_t)n * 2 * 4);
  u16*  x1bf = (u16*)alloc((size_t)n * 128 * 2);
  float* qq   = (float*)alloc((size_t)n * 64 * 4);
  u8*   kv8  = (u8*)alloc((size_t)n * 128);         // fp8 chunk-interleaved [k|v]
  float* skip = (float*)alloc((size_t)n * 64 * 4);
  int* offsets = (int*)alloc((size_t)(n + 1) * 4);
  int* csr     = (int*)alloc((size_t)E * 4);
  int* bc      = (int*)alloc(516 * 4);
  int* bbase   = (int*)alloc(516 * 4);
  int* bcur    = (int*)alloc(516 * 4);
  u16*  w1t  = (u16*)alloc((size_t)128 * 128 * 2);
  u16*  wt2  = (u16*)alloc((size_t)256 * 128 * 2);
  u16*  wxt  = (u16*)alloc((size_t)16 * 128 * 2);
  uint2* ebuf = (uint2*)xbf;                        // alias: xbf dead after gemm1

  int eblocks = (E + 4095) / 4096;

  // prep + GEMM1 (xbf consumed before ebuf aliasing)
  hipMemsetAsync(bc, 0, 513 * 4, stream);
  cast_x_kernel<<<(n * 16 + 255) / 256, 256, 0, stream>>>(x, xbf, n * 16);
  prep_w_kernel<<<200, 256, 0, stream>>>(W1, Wq, Wk, Wv, Ws, att_src, att_dst,
                                         w1t, wt2, wxt);
  gemm1_mfma<<<(n + 63) / 64, 256, 0, stream>>>(xbf, w1t, wxt, h2, asrc, adst, n);

  // CSR build via multisplit
  bucket_hist_kernel<<<eblocks, 256, 0, stream>>>(dst, bc, E);
  bucket_scan_kernel<<<1, 256, 0, stream>>>(bc, bbase, bcur);
  multisplit_kernel<<<eblocks, 256, 0, stream>>>(src, dst, bcur, ebuf, E);
  bucket_csr_kernel<<<nb, 256, 0, stream>>>(ebuf, bbase, offsets, csr, n, E, nb);

  // GAT aggregation
  gat_agg_kernel<<<(n + 3) / 4, 256, 0, stream>>>(h2, asrc, adst, offsets, csr, b1, x1bf, n);

  // Transformer layer
  gemm2_mfma<<<(n + 63) / 64, 256, 0, stream>>>(x1bf, wt2, bq, bk, bv, bs,
                                                qq, kv8, skip, n);
  trans_agg_kernel<<<(n + 3) / 4, 256, 0, stream>>>(qq, kv8, skip, offsets, csr,
                                                    out, n);
}